// Round 10
// baseline (5406.607 us; speedup 1.0000x reference)
//
#include <hip/hip_runtime.h>
#include <hip/hip_fp16.h>
#include <stdint.h>

#define B_  32
#define T_  2000
#define H_  512
#define NH_ 100
#define NM_ 65

typedef _Float16 f16x8 __attribute__((ext_vector_type(8)));
typedef _Float16 f16x2 __attribute__((ext_vector_type(2)));
typedef float    f32x4 __attribute__((ext_vector_type(4)));

typedef __attribute__((address_space(3))) void lds_void_t;
typedef __attribute__((address_space(1))) void glb_void_t;

__device__ __forceinline__ void gload_lds16(const void* g, void* l) {
  __builtin_amdgcn_global_load_lds((const glb_void_t*)g, (lds_void_t*)l, 16, 0, 0);
}

__device__ __forceinline__ float sigmoidf_(float x) {
  float e = __builtin_amdgcn_exp2f(-x * 1.44269504f);
  return __builtin_amdgcn_rcpf(1.0f + e);
}
__device__ __forceinline__ float tanhf_(float x) {
  float e = __builtin_amdgcn_exp2f(x * 2.88539008f);
  return 1.0f - 2.0f * __builtin_amdgcn_rcpf(e + 1.0f);
}
__device__ __forceinline__ float dot2(unsigned w, unsigned h, float acc) {
  return __builtin_amdgcn_fdot2(__builtin_bit_cast(f16x2, w),
                                __builtin_bit_cast(f16x2, h), acc, false);
}
__device__ __forceinline__ unsigned pack2(float a, float b) {
  __half2 h = __floats2half2_rn(a, b);
  return __builtin_bit_cast(unsigned, h);
}
// swizzled u32 slot for h-pair i: spreads the 8 col-slices across distinct
// bank-quads so gemv b128 reads are conflict-free.
__device__ __forceinline__ int wslot(int i) {
  int q = i >> 5;
  return (q << 5) + (((((i >> 2) & 7) ^ q)) << 2) + (i & 3);
}

// ---------------- hypernetwork ----------------
__global__ void hyper1(const float* __restrict__ es, const float* __restrict__ W1,
                       const float* __restrict__ b1, float* __restrict__ hE) {
  int b = blockIdx.x, o = threadIdx.x;   // 32 x 256
  float a = b1[o];
  #pragma unroll
  for (int c = 0; c < 16; ++c) a += es[b*16 + c] * W1[o*16 + c];
  hE[b*256 + o] = fmaxf(a, 0.f);
}

__global__ void hyper2(const float* __restrict__ hE,
                       const float* __restrict__ Wbh, const float* __restrict__ bbh,
                       const float* __restrict__ harmb,
                       const float* __restrict__ Wbn, const float* __restrict__ bbn,
                       const float* __restrict__ noiseb, float* __restrict__ effb) {
  int b = blockIdx.x, o = threadIdx.x;
  if (o < NH_) {
    float a = bbh[o] + harmb[o];
    for (int c = 0; c < 256; ++c) a += hE[b*256 + c] * Wbh[o*256 + c];
    effb[b*256 + o] = a;
  } else if (o < NH_ + NM_) {
    int q = o - NH_;
    float a = bbn[q] + noiseb[q];
    for (int c = 0; c < 256; ++c) a += hE[b*256 + c] * Wbn[q*256 + c];
    effb[b*256 + o] = a;
  }
}

// effW[b][o_base+o][h] = baseW[o*512+h] + bd[row] + sum_c Wd[row][c]*hE[b][c]
__global__ __launch_bounds__(256) void hyper3(
    const float* __restrict__ hE, const float* __restrict__ Wd,
    const float* __restrict__ bd, const float* __restrict__ baseW,
    __half* __restrict__ effW, int o_base) {
  __shared__ float wl[256*33];
  __shared__ float hEl[32*256];
  int tid = threadIdx.x;
  int row0 = blockIdx.x * 256;
  #pragma unroll
  for (int i = 0; i < 32; ++i) hEl[i*256 + tid] = hE[i*256 + tid];
  float acc[32];
  #pragma unroll
  for (int b = 0; b < 32; ++b) acc[b] = 0.f;
  for (int cc = 0; cc < 256; cc += 32) {
    __syncthreads();
    #pragma unroll
    for (int i = 0; i < 32; ++i) {
      int idx = i*256 + tid;
      int r = idx >> 5, c = idx & 31;
      wl[r*33 + c] = Wd[(size_t)(row0 + r)*256 + cc + c];
    }
    __syncthreads();
    #pragma unroll
    for (int c = 0; c < 32; ++c) {
      float w = wl[tid*33 + c];
      #pragma unroll
      for (int b = 0; b < 32; ++b) acc[b] += w * hEl[b*256 + cc + c];
    }
  }
  int row = row0 + tid;
  int o = row >> 9, h = row & 511;
  float base = baseW[row] + bd[row];
  #pragma unroll
  for (int b = 0; b < 32; ++b) {
    effW[((size_t)b*256 + o_base + o)*512 + h] = (__half)(acc[b] + base);
  }
}

// ---------------- converts ----------------
__global__ void cvt_f16(const float* __restrict__ in, __half* __restrict__ out, int n) {
  int i = blockIdx.x*256 + threadIdx.x;
  if (i < n) out[i] = (__half)in[i];
}

// Wp5[(w*24 + k)*512 + t]: WG w, thread t=(u*8+cs) owns 3 gates of unit w*64+u,
// cols cs*64..+64. k = g*8+kk: row = g*512 + w*64 + u, cols = cs*64 + kk*8 ..+8
__global__ void pack_whh5(const float* __restrict__ Whh, uint4* __restrict__ Wp) {
  int idx = blockIdx.x*256 + threadIdx.x;    // 8*24*512 = 98304
  int t = idx & 511;
  int k = (idx >> 9) % 24;
  int w = idx / (512*24);
  int g = k >> 3, kk = k & 7;
  int u = t >> 3, cs = t & 7;
  int row = g*512 + w*64 + u;
  int col0 = cs*64 + kk*8;
  const float* src = Whh + (size_t)row*512 + col0;
  uint4 o;
  o.x = pack2(src[0], src[1]);
  o.y = pack2(src[2], src[3]);
  o.z = pack2(src[4], src[5]);
  o.w = pack2(src[6], src[7]);
  Wp[idx] = o;
}

// ---------------- pre layer (per chunk) ----------------
__global__ void pre_kernel(const float* __restrict__ f0, const float* __restrict__ loud,
                           const float* __restrict__ preW, const float* __restrict__ preb,
                           __half* __restrict__ xpre, int CH, int c0) {
  int b = blockIdx.y;
  int idx = blockIdx.x*256 + threadIdx.x;    // CH*512
  int t = idx >> 9, h = idx & 511;
  int mg = b*T_ + c0 + t;
  float v = f0[mg]*preW[h*2+0] + loud[mg]*preW[h*2+1] + preb[h];
  v = v >= 0.f ? v : 0.01f*v;
  xpre[((size_t)b*CH + t)*512 + h] = (__half)v;
}

// ---------------- trunk GEMM (NT, K=512, 128x128 tile, f16 MFMA) ----------------
template<int ACT>
__global__ __launch_bounds__(256) void gemm_nt(
    const __half* __restrict__ A, const __half* __restrict__ B,
    __half* __restrict__ C, const float* __restrict__ bias, int N) {
  constexpr int K = 512;
  __shared__ __align__(16) __half As[128*64];
  __shared__ __align__(16) __half Bs[128*64];
  int tid = threadIdx.x;
  int bx = blockIdx.x, by = blockIdx.y;
  const __half* Ab = A + (size_t)bx*128*K;
  const __half* Bb = B + (size_t)by*128*K;
  f32x4 acc[4][4] = {};
  int lane = tid & 63;
  int wv = tid >> 6, wr = wv >> 1, wc = wv & 1;
  int lr = lane & 15, lk = lane >> 4;

  for (int kt = 0; kt < K/64; ++kt) {
    #pragma unroll
    for (int j = 0; j < 4; ++j) {
      int idx = j*256 + tid;
      int row = idx >> 3, seg = idx & 7;
      const __half* gpA = Ab + (size_t)row*K + kt*64 + seg*8;
      const __half* gpB = Bb + (size_t)row*K + kt*64 + seg*8;
      __half* lpA = As + (size_t)(j*256 + (tid & ~63))*8;
      __half* lpB = Bs + (size_t)(j*256 + (tid & ~63))*8;
      gload_lds16(gpA, lpA);
      gload_lds16(gpB, lpB);
    }
    __syncthreads();
    #pragma unroll
    for (int ks = 0; ks < 2; ++ks) {
      f16x8 af[4], bf[4];
      #pragma unroll
      for (int i = 0; i < 4; ++i)
        af[i] = *(const f16x8*)(As + (wr*64 + i*16 + lr)*64 + ks*32 + lk*8);
      #pragma unroll
      for (int j2 = 0; j2 < 4; ++j2)
        bf[j2] = *(const f16x8*)(Bs + (wc*64 + j2*16 + lr)*64 + ks*32 + lk*8);
      #pragma unroll
      for (int i = 0; i < 4; ++i)
        #pragma unroll
        for (int j2 = 0; j2 < 4; ++j2)
          acc[i][j2] = __builtin_amdgcn_mfma_f32_16x16x32_f16(af[i], bf[j2], acc[i][j2], 0, 0, 0);
    }
    __syncthreads();
  }

  #pragma unroll
  for (int j2 = 0; j2 < 4; ++j2) {
    int col = by*128 + wc*64 + j2*16 + lr;
    float bv = bias[col];
    #pragma unroll
    for (int i = 0; i < 4; ++i) {
      int row0 = bx*128 + wr*64 + i*16 + lk*4;
      #pragma unroll
      for (int r = 0; r < 4; ++r) {
        float v = acc[i][j2][r] + bv;
        if (ACT == 1) v = v >= 0.f ? v : 0.01f*v;
        C[(size_t)(row0 + r)*N + col] = (__half)v;
      }
    }
  }
}

// ---------------- heads GEMM: per-batch modulated weights, sigmoid, fp32 out ----------------
__global__ __launch_bounds__(256) void heads_gemm(
    const __half* __restrict__ Apc, const __half* __restrict__ effW,
    const float* __restrict__ effb, float* __restrict__ out, int CH, int c0) {
  constexpr int K = 512;
  __shared__ __align__(16) __half As[128*64];
  __shared__ __align__(16) __half Bs[128*64];
  int tid = threadIdx.x;
  int bx = blockIdx.x, by = blockIdx.y, b = blockIdx.z;
  const __half* Ab = Apc + (size_t)b*CH*K;
  const __half* Bb = effW + ((size_t)b*256 + (size_t)by*128)*K;
  f32x4 acc[4][4] = {};
  int lane = tid & 63;
  int wv = tid >> 6, wr = wv >> 1, wc = wv & 1;
  int lr = lane & 15, lk = lane >> 4;

  for (int kt = 0; kt < K/64; ++kt) {
    #pragma unroll
    for (int j = 0; j < 4; ++j) {
      int idx = j*256 + tid;
      int row = idx >> 3, seg = idx & 7;
      int ar = bx*128 + row; if (ar > CH-1) ar = CH-1;
      const __half* gpA = Ab + (size_t)ar*K + kt*64 + seg*8;
      const __half* gpB = Bb + (size_t)row*K + kt*64 + seg*8;
      __half* lpA = As + (size_t)(j*256 + (tid & ~63))*8;
      __half* lpB = Bs + (size_t)(j*256 + (tid & ~63))*8;
      gload_lds16(gpA, lpA);
      gload_lds16(gpB, lpB);
    }
    __syncthreads();
    #pragma unroll
    for (int ks = 0; ks < 2; ++ks) {
      f16x8 af[4], bf[4];
      #pragma unroll
      for (int i = 0; i < 4; ++i)
        af[i] = *(const f16x8*)(As + (wr*64 + i*16 + lr)*64 + ks*32 + lk*8);
      #pragma unroll
      for (int j2 = 0; j2 < 4; ++j2)
        bf[j2] = *(const f16x8*)(Bs + (wc*64 + j2*16 + lr)*64 + ks*32 + lk*8);
      #pragma unroll
      for (int i = 0; i < 4; ++i)
        #pragma unroll
        for (int j2 = 0; j2 < 4; ++j2)
          acc[i][j2] = __builtin_amdgcn_mfma_f32_16x16x32_f16(af[i], bf[j2], acc[i][j2], 0, 0, 0);
    }
    __syncthreads();
  }

  #pragma unroll
  for (int j2 = 0; j2 < 4; ++j2) {
    int o = by*128 + wc*64 + j2*16 + lr;
    if (o < NH_ + NM_) {
      float bv = effb[b*256 + o];
      #pragma unroll
      for (int i = 0; i < 4; ++i) {
        #pragma unroll
        for (int r = 0; r < 4; ++r) {
          int trow = bx*128 + wr*64 + i*16 + lk*4 + r;
          if (trow < CH) {
            int tg = c0 + trow;
            float v = sigmoidf_(acc[i][j2][r] + bv);
            if (o < NH_)
              out[((size_t)b*T_ + tg)*NH_ + o] = v;
            else
              out[(size_t)B_*T_*NH_ + ((size_t)b*T_ + tg)*NM_ + (o - NH_)] = v;
          }
        }
      }
    }
  }
}

// ---------------- GRU scan: 8 WGs/batch, unit-major + DPP reduce, 1 barrier/step ----
// Round-9 budget closure: step 4300cyc = DS pipe ~1100 (48 b128 + 72 shfl=ds_bpermute
// + part/hq writes) + combine 300 + LLC RT ~1500 + 2 barrier phases. Fixes:
// (1) 8-lane col-reduce via DPP v_add (quad_perm 0xB1/0x4E + row_half_mirror 0x141)
//     -> zero DS ops for reduction; (2) thread (u,cs) holds ALL 3 gates of unit
//     w*64+u (24 uint4 = 96 VGPR, all 8 waves) -> after DPP, lane cs==0 combines
//     LOCALLY (h_old in register; no part[], no B1, no combine wave); (3) hq parity
//     double-buffer -> ONE lgkmcnt-only barrier per step. Publish/poll protocol
//     unchanged (tag-safe; cross-chunk stale residue CH-1/CH never matches 1,2).
#define LOADW(k) { const uint4* p_ = Wp + ((size_t)(w*24 + (k)))*512 + t; \
  asm volatile("global_load_dwordx4 %0, %1, off" : "=v"(wq_##k) : "v"(p_) : "memory"); }

#define DOTU(W, hv, A) { A = dot2(W.x, hv.x, A); A = dot2(W.y, hv.y, A); \
                         A = dot2(W.z, hv.z, A); A = dot2(W.w, hv.w, A); }

#define GS(kr, kz, kn, kk) { uint4 hv = hq4[(cs << 3) + ((kk) ^ cs)]; \
  DOTU(wq_##kr, hv, ar) DOTU(wq_##kz, hv, az) DOTU(wq_##kn, hv, an) }

#define DPPADD(a, ctrl) ((a) + __builtin_bit_cast(float, \
  __builtin_amdgcn_update_dpp(0, __builtin_bit_cast(int, (a)), (ctrl), 0xF, 0xF, true)))

#define BARX() do { asm volatile("s_waitcnt lgkmcnt(0)\n\ts_barrier" ::: "memory"); \
                    __builtin_amdgcn_sched_barrier(0); } while (0)

__global__ __launch_bounds__(512) __attribute__((amdgpu_waves_per_eu(2, 4)))
void gru_scan9(
    const uint4* __restrict__ Wp, const __half* __restrict__ gi_c,
    const float* __restrict__ bhh, __half* __restrict__ ys_c,
    float* __restrict__ hstate, unsigned long long* __restrict__ xch64,
    int CH, int first) {
  int wg = blockIdx.x;
  int b = wg & 31;            // batch
  int w = wg >> 5;            // unit-block 0..7 (units w*64 .. +64)
  int t = threadIdx.x;
  int u = t >> 3, cs = t & 7;

  __shared__ __align__(16) unsigned hq[2][264];   // parity double-buffered, swizzled

  uint4 wq_0{},wq_1{},wq_2{},wq_3{},wq_4{},wq_5{},wq_6{},wq_7{},
        wq_8{},wq_9{},wq_10{},wq_11{},wq_12{},wq_13{},wq_14{},wq_15{},
        wq_16{},wq_17{},wq_18{},wq_19{},wq_20{},wq_21{},wq_22{},wq_23{};
  LOADW(0)  LOADW(1)  LOADW(2)  LOADW(3)  LOADW(4)  LOADW(5)  LOADW(6)  LOADW(7)
  LOADW(8)  LOADW(9)  LOADW(10) LOADW(11) LOADW(12) LOADW(13) LOADW(14) LOADW(15)
  LOADW(16) LOADW(17) LOADW(18) LOADW(19) LOADW(20) LOADW(21) LOADW(22) LOADW(23)
  asm volatile("s_waitcnt vmcnt(0)" ::: "memory");
  __builtin_amdgcn_sched_barrier(0);

  int ug = w*64 + u;
  float br = 0.f, bz = 0.f, bn = 0.f, hreg = 0.f;
  if (cs == 0) {
    br = bhh[ug]; bz = bhh[512 + ug]; bn = bhh[1024 + ug];
    hreg = first ? 0.f : hstate[b*512 + ug];
  }
  if (t < 256) {
    unsigned hv0 = first ? 0u : pack2(hstate[b*512 + 2*t], hstate[b*512 + 2*t + 1]);
    hq[0][wslot(t)] = hv0;
  }
  __syncthreads();

  const __half* gib = gi_c + (size_t)b*CH*1536;
  __half* ysb = ys_c + (size_t)b*CH*512;

  // gi register prefetch (cs==0 lanes), one step ahead
  float gr_c = 0.f, gz_c = 0.f, gn_c = 0.f, gr_n = 0.f, gz_n = 0.f, gn_n = 0.f;
  if (cs == 0) {
    gr_c = (float)gib[ug]; gz_c = (float)gib[512 + ug]; gn_c = (float)gib[1024 + ug];
  }

  for (int s = 0; s < CH; ++s) {
    int p = s & 1;
    unsigned long long* xp64 = xch64 + ((size_t)p*32 + b)*256;

    if (cs == 0 && s + 1 < CH) {
      const __half* g1 = gib + (size_t)(s + 1)*1536 + ug;
      gr_n = (float)g1[0]; gz_n = (float)g1[512]; gn_n = (float)g1[1024];
    }

    const uint4* hq4 = (const uint4*)&hq[p][0];
    float ar = 0.f, az = 0.f, an = 0.f;
    GS(0,8,16,0)  GS(1,9,17,1)  GS(2,10,18,2)  GS(3,11,19,3)
    GS(4,12,20,4) GS(5,13,21,5) GS(6,14,22,6)  GS(7,15,23,7)

    // 8-lane column reduce on the VALU (DPP), not the DS pipe
    ar = DPPADD(ar, 0xB1); ar = DPPADD(ar, 0x4E); ar = DPPADD(ar, 0x141);
    az = DPPADD(az, 0xB1); az = DPPADD(az, 0x4E); az = DPPADD(az, 0x141);
    an = DPPADD(an, 0xB1); an = DPPADD(an, 0x4E); an = DPPADD(an, 0x141);

    if (cs == 0) {
      float r = sigmoidf_(gr_c + ar + br);
      float z = sigmoidf_(gz_c + az + bz);
      float n = tanhf_(gn_c + r*(an + bn));
      float h = (1.f - z)*n + z*hreg;
      hreg = h;
      unsigned myh = pack2(h, 0.f);                 // low 16 = f16(h)
      unsigned oth = (unsigned)__builtin_amdgcn_update_dpp(
          0, (int)myh, 0x128, 0xF, 0xF, true);      // row_ror:8 -> partner lane (u^1)
      if (!(u & 1)) {
        unsigned hv = (oth << 16) | myh;
        int pi = (w << 5) + (u >> 1);
        hq[p ^ 1][wslot(pi)] = hv;                  // own slice -> LDS
        *(unsigned*)&ysb[(size_t)s*512 + ug] = hv;  // ys (background store)
        unsigned long long tv = ((unsigned long long)(unsigned)(s + 1) << 32)
                                | (unsigned long long)hv;
        __hip_atomic_store(&xp64[pi], tv,
                           __ATOMIC_RELAXED, __HIP_MEMORY_SCOPE_AGENT);
      }
      if (s == CH - 1) hstate[b*512 + ug] = h;
      gr_c = gr_n; gz_c = gz_n; gn_c = gn_n;
    }
    if (t < 256 && (t >> 5) != w) {
      unsigned long long v;
      do {
        v = __hip_atomic_load(&xp64[t], __ATOMIC_RELAXED, __HIP_MEMORY_SCOPE_AGENT);
      } while ((unsigned)(v >> 32) != (unsigned)(s + 1));
      hq[p ^ 1][wslot(t)] = (unsigned)v;
    }
    BARX();   // hq[p^1] complete for next step
  }
}

// ---------------- launch ----------------
extern "C" void kernel_launch(void* const* d_in, const int* in_sizes, int n_in,
                              void* d_out, int out_size, void* d_ws, size_t ws_size,
                              hipStream_t stream) {
  const float* f0     = (const float*)d_in[0];
  const float* loud   = (const float*)d_in[1];
  const float* es     = (const float*)d_in[2];
  const float* preW   = (const float*)d_in[3];
  const float* preb   = (const float*)d_in[4];
  const float* Wih    = (const float*)d_in[5];
  const float* Whh    = (const float*)d_in[6];
  const float* b_ih   = (const float*)d_in[7];
  const float* b_hh   = (const float*)d_in[8];
  const float* postW  = (const float*)d_in[9];
  const float* postb  = (const float*)d_in[10];
  const float* harmW  = (const float*)d_in[11];
  const float* harmb  = (const float*)d_in[12];
  const float* noiseW = (const float*)d_in[13];
  const float* noiseb = (const float*)d_in[14];
  const float* hypW1  = (const float*)d_in[15];
  const float* hypb1  = (const float*)d_in[16];
  const float* Wdh    = (const float*)d_in[17];
  const float* bdh    = (const float*)d_in[18];
  const float* Wbh    = (const float*)d_in[19];
  const float* bbh    = (const float*)d_in[20];
  const float* Wdn    = (const float*)d_in[21];
  const float* bdn    = (const float*)d_in[22];
  const float* Wbn    = (const float*)d_in[23];
  const float* bbn    = (const float*)d_in[24];
  (void)in_sizes; (void)n_in; (void)out_size;

  const size_t FIXED = 13312ull*1024ull;   // ~13 MB fixed region
  int CH = 20;
  {
    const int opts[8] = {2000, 1000, 500, 400, 200, 100, 40, 20};
    for (int i = 0; i < 8; ++i) {
      size_t need = FIXED + (size_t)opts[i] * 163840ull + 65536ull;
      if (need <= ws_size) { CH = opts[i]; break; }
    }
  }
  const int NC = T_ / CH;
  const int Mc = B_ * CH;

  char* w = (char*)d_ws;
  size_t off = 0;
  auto alloc = [&](size_t bytes) -> void* {
    void* p = (void*)(w + off);
    off += (bytes + 255) & ~(size_t)255;
    return p;
  };
  float*    hE      = (float*)alloc((size_t)32*256*4);
  float*    effb    = (float*)alloc((size_t)32*256*4);
  float*    hstate  = (float*)alloc((size_t)32*512*4);
  __half*   effW    = (__half*)alloc((size_t)32*256*512*2);
  __half*   Wih16   = (__half*)alloc((size_t)1536*512*2);
  __half*   postW16 = (__half*)alloc((size_t)512*512*2);
  uint4*    Wp      = (uint4*)alloc((size_t)8*24*512*16 + 4096);
  unsigned long long* xch64 = (unsigned long long*)alloc((size_t)2*32*256*8);
  __half*   xpre    = (__half*)alloc((size_t)Mc*512*2);
  __half*   gibuf   = (__half*)alloc((size_t)Mc*1536*2);
  __half*   ysbuf   = (__half*)alloc((size_t)Mc*512*2);
  __half*   postc   = xpre;   // xpre dead after gi GEMM

  hyper1<<<32, 256, 0, stream>>>(es, hypW1, hypb1, hE);
  hyper2<<<32, 256, 0, stream>>>(hE, Wbh, bbh, harmb, Wbn, bbn, noiseb, effb);
  hyper3<<<200, 256, 0, stream>>>(hE, Wdh, bdh, harmW, effW, 0);
  hyper3<<<130, 256, 0, stream>>>(hE, Wdn, bdn, noiseW, effW, NH_);
  cvt_f16<<<(1536*512)/256, 256, 0, stream>>>(Wih, Wih16, 1536*512);
  cvt_f16<<<(512*512)/256, 256, 0, stream>>>(postW, postW16, 512*512);
  pack_whh5<<<384, 256, 0, stream>>>(Whh, Wp);

  for (int c = 0; c < NC; ++c) {
    int c0 = c * CH;
    pre_kernel<<<dim3(CH*2, 32), 256, 0, stream>>>(f0, loud, preW, preb, xpre, CH, c0);
    gemm_nt<0><<<dim3(Mc/128, 12), 256, 0, stream>>>(xpre, Wih16, gibuf, b_ih, 1536);
    gru_scan9<<<256, 512, 0, stream>>>(Wp, gibuf, b_hh, ysbuf, hstate, xch64,
                                       CH, c == 0 ? 1 : 0);
    gemm_nt<1><<<dim3(Mc/128, 4), 256, 0, stream>>>(ysbuf, postW16, postc, postb, 512);
    heads_gemm<<<dim3((CH+127)/128, 2, 32), 256, 0, stream>>>(postc, effW, effb,
                                                              (float*)d_out, CH, c0);
  }
}

// Round 11
// 4614.227 us; speedup vs baseline: 1.1717x; 1.1717x over previous
//
#include <hip/hip_runtime.h>
#include <hip/hip_fp16.h>
#include <stdint.h>

#define B_  32
#define T_  2000
#define H_  512
#define NH_ 100
#define NM_ 65

typedef _Float16 f16x8 __attribute__((ext_vector_type(8)));
typedef _Float16 f16x2 __attribute__((ext_vector_type(2)));
typedef float    f32x4 __attribute__((ext_vector_type(4)));

typedef __attribute__((address_space(3))) void lds_void_t;
typedef __attribute__((address_space(1))) void glb_void_t;

__device__ __forceinline__ void gload_lds16(const void* g, void* l) {
  __builtin_amdgcn_global_load_lds((const glb_void_t*)g, (lds_void_t*)l, 16, 0, 0);
}

__device__ __forceinline__ float sigmoidf_(float x) {
  float e = __builtin_amdgcn_exp2f(-x * 1.44269504f);
  return __builtin_amdgcn_rcpf(1.0f + e);
}
__device__ __forceinline__ float tanhf_(float x) {
  float e = __builtin_amdgcn_exp2f(x * 2.88539008f);
  return 1.0f - 2.0f * __builtin_amdgcn_rcpf(e + 1.0f);
}
__device__ __forceinline__ float dot2(unsigned w, unsigned h, float acc) {
  return __builtin_amdgcn_fdot2(__builtin_bit_cast(f16x2, w),
                                __builtin_bit_cast(f16x2, h), acc, false);
}
__device__ __forceinline__ unsigned pack2(float a, float b) {
  __half2 h = __floats2half2_rn(a, b);
  return __builtin_bit_cast(unsigned, h);
}
__device__ __forceinline__ float hsel(unsigned w, int hi) {
  __half2 h2 = __builtin_bit_cast(__half2, w);
  return hi ? __high2float(h2) : __low2float(h2);
}
__device__ __forceinline__ int hq_swz(int i) {
  int cs = i >> 5, kk = (i >> 2) & 7;
  return cs*32 + ((kk ^ cs) << 2) + (i & 3);
}
// sc0 load: bypass L1, served by XCD L2 (fast same-XCD mailbox read)
__device__ __forceinline__ unsigned long long ld64_sc0(const unsigned long long* p) {
  unsigned long long v;
  asm volatile("global_load_dwordx2 %0, %1, off sc0" : "=v"(v) : "v"(p));
  asm volatile("s_waitcnt vmcnt(0)" ::: "memory");
  return v;
}

// ---------------- hypernetwork ----------------
__global__ void hyper1(const float* __restrict__ es, const float* __restrict__ W1,
                       const float* __restrict__ b1, float* __restrict__ hE) {
  int b = blockIdx.x, o = threadIdx.x;   // 32 x 256
  float a = b1[o];
  #pragma unroll
  for (int c = 0; c < 16; ++c) a += es[b*16 + c] * W1[o*16 + c];
  hE[b*256 + o] = fmaxf(a, 0.f);
}

__global__ void hyper2(const float* __restrict__ hE,
                       const float* __restrict__ Wbh, const float* __restrict__ bbh,
                       const float* __restrict__ harmb,
                       const float* __restrict__ Wbn, const float* __restrict__ bbn,
                       const float* __restrict__ noiseb, float* __restrict__ effb) {
  int b = blockIdx.x, o = threadIdx.x;
  if (o < NH_) {
    float a = bbh[o] + harmb[o];
    for (int c = 0; c < 256; ++c) a += hE[b*256 + c] * Wbh[o*256 + c];
    effb[b*256 + o] = a;
  } else if (o < NH_ + NM_) {
    int q = o - NH_;
    float a = bbn[q] + noiseb[q];
    for (int c = 0; c < 256; ++c) a += hE[b*256 + c] * Wbn[q*256 + c];
    effb[b*256 + o] = a;
  }
}

// effW[b][o_base+o][h] = baseW[o*512+h] + bd[row] + sum_c Wd[row][c]*hE[b][c]
__global__ __launch_bounds__(256) void hyper3(
    const float* __restrict__ hE, const float* __restrict__ Wd,
    const float* __restrict__ bd, const float* __restrict__ baseW,
    __half* __restrict__ effW, int o_base) {
  __shared__ float wl[256*33];
  __shared__ float hEl[32*256];
  int tid = threadIdx.x;
  int row0 = blockIdx.x * 256;
  #pragma unroll
  for (int i = 0; i < 32; ++i) hEl[i*256 + tid] = hE[i*256 + tid];
  float acc[32];
  #pragma unroll
  for (int b = 0; b < 32; ++b) acc[b] = 0.f;
  for (int cc = 0; cc < 256; cc += 32) {
    __syncthreads();
    #pragma unroll
    for (int i = 0; i < 32; ++i) {
      int idx = i*256 + tid;
      int r = idx >> 5, c = idx & 31;
      wl[r*33 + c] = Wd[(size_t)(row0 + r)*256 + cc + c];
    }
    __syncthreads();
    #pragma unroll
    for (int c = 0; c < 32; ++c) {
      float w = wl[tid*33 + c];
      #pragma unroll
      for (int b = 0; b < 32; ++b) acc[b] += w * hEl[b*256 + cc + c];
    }
  }
  int row = row0 + tid;
  int o = row >> 9, h = row & 511;
  float base = baseW[row] + bd[row];
  #pragma unroll
  for (int b = 0; b < 32; ++b) {
    effW[((size_t)b*256 + o_base + o)*512 + h] = (__half)(acc[b] + base);
  }
}

// ---------------- converts ----------------
__global__ void cvt_f16(const float* __restrict__ in, __half* __restrict__ out, int n) {
  int i = blockIdx.x*256 + threadIdx.x;
  if (i < n) out[i] = (__half)in[i];
}

// Wp4[(w*32 + k)*384 + t]: thread t = rq*8+cs owns 4 rows x 64 cols.
// k = j*8 + kk: row = (rq>>4)*512 + w*64 + (rq&15)*4 + j, cols = cs*64 + kk*8 ..+8
__global__ void pack_whh4(const float* __restrict__ Whh, uint4* __restrict__ Wp) {
  int idx = blockIdx.x*256 + threadIdx.x;    // 8*32*384 = 98304
  int t = idx % 384;
  int k = (idx / 384) & 31;
  int w = idx / (384*32);
  int rq = t >> 3, cs = t & 7;
  int j = k >> 3, kk = k & 7;
  int row = (rq >> 4)*512 + w*64 + (rq & 15)*4 + j;
  int col0 = cs*64 + kk*8;
  const float* src = Whh + (size_t)row*512 + col0;
  uint4 o;
  o.x = pack2(src[0], src[1]);
  o.y = pack2(src[2], src[3]);
  o.z = pack2(src[4], src[5]);
  o.w = pack2(src[6], src[7]);
  Wp[idx] = o;
}

// ---------------- pre layer (per chunk) ----------------
__global__ void pre_kernel(const float* __restrict__ f0, const float* __restrict__ loud,
                           const float* __restrict__ preW, const float* __restrict__ preb,
                           __half* __restrict__ xpre, int CH, int c0) {
  int b = blockIdx.y;
  int idx = blockIdx.x*256 + threadIdx.x;    // CH*512
  int t = idx >> 9, h = idx & 511;
  int mg = b*T_ + c0 + t;
  float v = f0[mg]*preW[h*2+0] + loud[mg]*preW[h*2+1] + preb[h];
  v = v >= 0.f ? v : 0.01f*v;
  xpre[((size_t)b*CH + t)*512 + h] = (__half)v;
}

// ---------------- trunk GEMM (NT, K=512, 128x128 tile, f16 MFMA) ----------------
template<int ACT>
__global__ __launch_bounds__(256) void gemm_nt(
    const __half* __restrict__ A, const __half* __restrict__ B,
    __half* __restrict__ C, const float* __restrict__ bias, int N) {
  constexpr int K = 512;
  __shared__ __align__(16) __half As[128*64];
  __shared__ __align__(16) __half Bs[128*64];
  int tid = threadIdx.x;
  int bx = blockIdx.x, by = blockIdx.y;
  const __half* Ab = A + (size_t)bx*128*K;
  const __half* Bb = B + (size_t)by*128*K;
  f32x4 acc[4][4] = {};
  int lane = tid & 63;
  int wv = tid >> 6, wr = wv >> 1, wc = wv & 1;
  int lr = lane & 15, lk = lane >> 4;

  for (int kt = 0; kt < K/64; ++kt) {
    #pragma unroll
    for (int j = 0; j < 4; ++j) {
      int idx = j*256 + tid;
      int row = idx >> 3, seg = idx & 7;
      const __half* gpA = Ab + (size_t)row*K + kt*64 + seg*8;
      const __half* gpB = Bb + (size_t)row*K + kt*64 + seg*8;
      __half* lpA = As + (size_t)(j*256 + (tid & ~63))*8;
      __half* lpB = Bs + (size_t)(j*256 + (tid & ~63))*8;
      gload_lds16(gpA, lpA);
      gload_lds16(gpB, lpB);
    }
    __syncthreads();
    #pragma unroll
    for (int ks = 0; ks < 2; ++ks) {
      f16x8 af[4], bf[4];
      #pragma unroll
      for (int i = 0; i < 4; ++i)
        af[i] = *(const f16x8*)(As + (wr*64 + i*16 + lr)*64 + ks*32 + lk*8);
      #pragma unroll
      for (int j2 = 0; j2 < 4; ++j2)
        bf[j2] = *(const f16x8*)(Bs + (wc*64 + j2*16 + lr)*64 + ks*32 + lk*8);
      #pragma unroll
      for (int i = 0; i < 4; ++i)
        #pragma unroll
        for (int j2 = 0; j2 < 4; ++j2)
          acc[i][j2] = __builtin_amdgcn_mfma_f32_16x16x32_f16(af[i], bf[j2], acc[i][j2], 0, 0, 0);
    }
    __syncthreads();
  }

  #pragma unroll
  for (int j2 = 0; j2 < 4; ++j2) {
    int col = by*128 + wc*64 + j2*16 + lr;
    float bv = bias[col];
    #pragma unroll
    for (int i = 0; i < 4; ++i) {
      int row0 = bx*128 + wr*64 + i*16 + lk*4;
      #pragma unroll
      for (int r = 0; r < 4; ++r) {
        float v = acc[i][j2][r] + bv;
        if (ACT == 1) v = v >= 0.f ? v : 0.01f*v;
        C[(size_t)(row0 + r)*N + col] = (__half)v;
      }
    }
  }
}

// ---------------- heads GEMM: per-batch modulated weights, sigmoid, fp32 out ----------------
__global__ __launch_bounds__(256) void heads_gemm(
    const __half* __restrict__ Apc, const __half* __restrict__ effW,
    const float* __restrict__ effb, float* __restrict__ out, int CH, int c0) {
  constexpr int K = 512;
  __shared__ __align__(16) __half As[128*64];
  __shared__ __align__(16) __half Bs[128*64];
  int tid = threadIdx.x;
  int bx = blockIdx.x, by = blockIdx.y, b = blockIdx.z;
  const __half* Ab = Apc + (size_t)b*CH*K;
  const __half* Bb = effW + ((size_t)b*256 + (size_t)by*128)*K;
  f32x4 acc[4][4] = {};
  int lane = tid & 63;
  int wv = tid >> 6, wr = wv >> 1, wc = wv & 1;
  int lr = lane & 15, lk = lane >> 4;

  for (int kt = 0; kt < K/64; ++kt) {
    #pragma unroll
    for (int j = 0; j < 4; ++j) {
      int idx = j*256 + tid;
      int row = idx >> 3, seg = idx & 7;
      int ar = bx*128 + row; if (ar > CH-1) ar = CH-1;
      const __half* gpA = Ab + (size_t)ar*K + kt*64 + seg*8;
      const __half* gpB = Bb + (size_t)row*K + kt*64 + seg*8;
      __half* lpA = As + (size_t)(j*256 + (tid & ~63))*8;
      __half* lpB = Bs + (size_t)(j*256 + (tid & ~63))*8;
      gload_lds16(gpA, lpA);
      gload_lds16(gpB, lpB);
    }
    __syncthreads();
    #pragma unroll
    for (int ks = 0; ks < 2; ++ks) {
      f16x8 af[4], bf[4];
      #pragma unroll
      for (int i = 0; i < 4; ++i)
        af[i] = *(const f16x8*)(As + (wr*64 + i*16 + lr)*64 + ks*32 + lk*8);
      #pragma unroll
      for (int j2 = 0; j2 < 4; ++j2)
        bf[j2] = *(const f16x8*)(Bs + (wc*64 + j2*16 + lr)*64 + ks*32 + lk*8);
      #pragma unroll
      for (int i = 0; i < 4; ++i)
        #pragma unroll
        for (int j2 = 0; j2 < 4; ++j2)
          acc[i][j2] = __builtin_amdgcn_mfma_f32_16x16x32_f16(af[i], bf[j2], acc[i][j2], 0, 0, 0);
    }
    __syncthreads();
  }

  #pragma unroll
  for (int j2 = 0; j2 < 4; ++j2) {
    int o = by*128 + wc*64 + j2*16 + lr;
    if (o < NH_ + NM_) {
      float bv = effb[b*256 + o];
      #pragma unroll
      for (int i = 0; i < 4; ++i) {
        #pragma unroll
        for (int r = 0; r < 4; ++r) {
          int trow = bx*128 + wr*64 + i*16 + lk*4 + r;
          if (trow < CH) {
            int tg = c0 + trow;
            float v = sigmoidf_(acc[i][j2][r] + bv);
            if (o < NH_)
              out[((size_t)b*T_ + tg)*NH_ + o] = v;
            else
              out[(size_t)B_*T_*NH_ + ((size_t)b*T_ + tg)*NM_ + (o - NH_)] = v;
          }
        }
      }
    }
  }
}

// ---------------- GRU scan: round-9 structure + dual-mailbox exchange ----
// r10 regressed -> reverted to r9 (4rows x 64cols gemv, shfl_xor col-reduce,
// wave-6 combine, 2 raw barriers). ONE change: the exchange. r7-r10 invariant:
// ~1.3us/step of wait survives all barrier/DS restructures -> agent-scope
// atomics are served at the cross-XCD coherence point (MALL, ~700cy/load).
// Batch b's 8 WGs are all == b (mod 8) -> same XCD under round-robin: its
// shared L2 (~250cy) can carry the exchange. Dual mailbox: publisher writes
// 8 per-destination private fast slots (plain stores, land in local L2) +
// the authoritative agent-scope slot. Reader polls its PRIVATE fast slot via
// sc0 load (bypass L1, hit L2), alternating with the slow slot; zeroes the
// fast slot after consuming -> if placement breaks co-location the reader
// sees its own 0 and falls back (correct for ANY placement, G16-safe; stale
// cross-launch data can never false-match a consumed-then-zeroed slot).
#define LOADW(k) { const uint4* p = Wp + ((size_t)(w*32 + (k)))*384 + t; \
  asm volatile("global_load_dwordx4 %0, %1, off" : "=v"(wq_##k) : "v"(p) : "memory"); }

#define DOT4(k, hv, A) { \
  A = dot2(wq_##k.x, hv.x, A); A = dot2(wq_##k.y, hv.y, A); \
  A = dot2(wq_##k.z, hv.z, A); A = dot2(wq_##k.w, hv.w, A); }

#define BARX() do { asm volatile("s_waitcnt lgkmcnt(0)\n\ts_barrier" ::: "memory"); \
                    __builtin_amdgcn_sched_barrier(0); } while (0)

__global__ __launch_bounds__(512) __attribute__((amdgpu_waves_per_eu(2, 4)))
void gru_scan8(
    const uint4* __restrict__ Wp, const __half* __restrict__ gi_c,
    const float* __restrict__ bhh, __half* __restrict__ ys_c,
    float* __restrict__ hstate, unsigned long long* __restrict__ xch64,
    unsigned long long* __restrict__ xfast, int CH, int first) {
  int wg = blockIdx.x;
  int b = wg & 31;            // batch
  int w = wg >> 5;            // unit-block 0..7 (units w*64 .. +64)
  int t = threadIdx.x;
  int rq = t >> 3, cs = t & 7;
  bool wact = (t < 384);      // waves 0-5 hold weights
  bool comb = (t >= 384 && t < 416);   // wave 6 lower half: combine
  int tc = t - 384;           // combine lane (units 2tc, 2tc+1)

  __shared__ __align__(16) unsigned hq[256];   // h packed f16x2, swizzled (hq_swz)
  __shared__ float part[192];                  // fully-reduced gate partials [g*64+u]
  __shared__ float gil[192];                   // gi slices for combine

  uint4 wq_0{},wq_1{},wq_2{},wq_3{},wq_4{},wq_5{},wq_6{},wq_7{},
        wq_8{},wq_9{},wq_10{},wq_11{},wq_12{},wq_13{},wq_14{},wq_15{},
        wq_16{},wq_17{},wq_18{},wq_19{},wq_20{},wq_21{},wq_22{},wq_23{},
        wq_24{},wq_25{},wq_26{},wq_27{},wq_28{},wq_29{},wq_30{},wq_31{};
  if (wact) {
    LOADW(0)  LOADW(1)  LOADW(2)  LOADW(3)  LOADW(4)  LOADW(5)  LOADW(6)  LOADW(7)
    LOADW(8)  LOADW(9)  LOADW(10) LOADW(11) LOADW(12) LOADW(13) LOADW(14) LOADW(15)
    LOADW(16) LOADW(17) LOADW(18) LOADW(19) LOADW(20) LOADW(21) LOADW(22) LOADW(23)
    LOADW(24) LOADW(25) LOADW(26) LOADW(27) LOADW(28) LOADW(29) LOADW(30) LOADW(31)
  }
  asm volatile("s_waitcnt vmcnt(0)" ::: "memory");
  __builtin_amdgcn_sched_barrier(0);

  // combine-wave biases (tc handles units 2tc, 2tc+1)
  float br0=0.f,br1=0.f,bz0=0.f,bz1=0.f,bn0=0.f,bn1=0.f;
  if (comb) {
    int u0 = w*64 + 2*tc;
    br0 = bhh[u0];        br1 = bhh[u0+1];
    bz0 = bhh[512+u0];    bz1 = bhh[512+u0+1];
    bn0 = bhh[1024+u0];   bn1 = bhh[1024+u0+1];
  }

  if (t < 256) {
    unsigned hv0 = first ? 0u : pack2(hstate[b*512 + 2*t], hstate[b*512 + 2*t + 1]);
    hq[hq_swz(t)] = hv0;
  }
  __syncthreads();

  const __half* gib = gi_c + (size_t)b*CH*1536;
  __half* ysb = ys_c + (size_t)b*CH*512;
  const uint4* hq4 = (const uint4*)hq;
  int hb = cs*8;

  // gi prefetch: giv_cur holds step-s value; load s+1 at loop top
  float giv_cur = 0.f, giv_next = 0.f;
  if (t < 192) giv_cur = (float)gib[(t >> 6)*512 + w*64 + (t & 63)];

  for (int s = 0; s < CH; ++s) {
    int p = s & 1;
    unsigned long long* xp64 = xch64 + ((size_t)p*32 + b)*256;
    unsigned long long* xfb  = xfast + (((size_t)p*32 + b)*8)*256;

    if (t < 192 && s + 1 < CH)
      giv_next = (float)gib[(size_t)(s+1)*1536 + (t >> 6)*512 + w*64 + (t & 63)];

    if (wact) {
      uint4 hv0_ = hq4[hb + (0 ^ cs)];
      uint4 hv1_ = hq4[hb + (1 ^ cs)];
      uint4 hv2_ = hq4[hb + (2 ^ cs)];
      uint4 hv3_ = hq4[hb + (3 ^ cs)];
      uint4 hv4_ = hq4[hb + (4 ^ cs)];
      uint4 hv5_ = hq4[hb + (5 ^ cs)];
      uint4 hv6_ = hq4[hb + (6 ^ cs)];
      uint4 hv7_ = hq4[hb + (7 ^ cs)];
      float a0 = 0.f, a1 = 0.f, a2 = 0.f, a3 = 0.f;
      DOT4(0,hv0_,a0)  DOT4(8,hv0_,a1)  DOT4(16,hv0_,a2) DOT4(24,hv0_,a3)
      DOT4(1,hv1_,a0)  DOT4(9,hv1_,a1)  DOT4(17,hv1_,a2) DOT4(25,hv1_,a3)
      DOT4(2,hv2_,a0)  DOT4(10,hv2_,a1) DOT4(18,hv2_,a2) DOT4(26,hv2_,a3)
      DOT4(3,hv3_,a0)  DOT4(11,hv3_,a1) DOT4(19,hv3_,a2) DOT4(27,hv3_,a3)
      DOT4(4,hv4_,a0)  DOT4(12,hv4_,a1) DOT4(20,hv4_,a2) DOT4(28,hv4_,a3)
      DOT4(5,hv5_,a0)  DOT4(13,hv5_,a1) DOT4(21,hv5_,a2) DOT4(29,hv5_,a3)
      DOT4(6,hv6_,a0)  DOT4(14,hv6_,a1) DOT4(22,hv6_,a2) DOT4(30,hv6_,a3)
      DOT4(7,hv7_,a0)  DOT4(15,hv7_,a1) DOT4(23,hv7_,a2) DOT4(31,hv7_,a3)
      // in-wave 8-way column reduce (cs lanes are adjacent: xor 1,2,4 stay in group)
      a0 += __shfl_xor(a0, 1); a0 += __shfl_xor(a0, 2); a0 += __shfl_xor(a0, 4);
      a1 += __shfl_xor(a1, 1); a1 += __shfl_xor(a1, 2); a1 += __shfl_xor(a1, 4);
      a2 += __shfl_xor(a2, 1); a2 += __shfl_xor(a2, 2); a2 += __shfl_xor(a2, 4);
      a3 += __shfl_xor(a3, 1); a3 += __shfl_xor(a3, 2); a3 += __shfl_xor(a3, 4);
      if (cs < 4) {
        float v = (cs == 0) ? a0 : (cs == 1) ? a1 : (cs == 2) ? a2 : a3;
        part[(rq << 2) + cs] = v;
      }
      if (t < 192) gil[t] = giv_cur;
    }
    giv_cur = giv_next;
    BARX();   // B1: part + gil visible

    if (comb) {
      int j0 = 2*tc, j1 = 2*tc + 1;
      float r0 = sigmoidf_(gil[j0] + part[j0] + br0);
      float r1 = sigmoidf_(gil[j1] + part[j1] + br1);
      float z0 = sigmoidf_(gil[64+j0] + part[64+j0] + bz0);
      float z1 = sigmoidf_(gil[64+j1] + part[64+j1] + bz1);
      float n0 = tanhf_(gil[128+j0] + r0*(part[128+j0] + bn0));
      float n1 = tanhf_(gil[128+j1] + r1*(part[128+j1] + bn1));
      int gidx = w*32 + tc;
      int hidx = hq_swz(gidx);
      unsigned hold = hq[hidx];
      float h0 = (1.f - z0)*n0 + z0*hsel(hold, 0);
      float h1 = (1.f - z1)*n1 + z1*hsel(hold, 1);
      unsigned hv = pack2(h0, h1);
      hq[hidx] = hv;                                              // own slice -> LDS
      *(unsigned*)&ysb[(size_t)s*512 + w*64 + j0] = hv;           // ys (background)
      unsigned long long tv = ((unsigned long long)(unsigned)(s + 1) << 32)
                              | (unsigned long long)hv;
      // fast path: private slot per destination WG (plain stores, local L2)
      #pragma unroll
      for (int d = 0; d < 8; ++d)
        __hip_atomic_store(&xfb[(size_t)d*256 + gidx], tv,
                           __ATOMIC_RELAXED, __HIP_MEMORY_SCOPE_WORKGROUP);
      // slow path: authoritative agent-scope slot (any placement)
      __hip_atomic_store(&xp64[gidx], tv,
                         __ATOMIC_RELAXED, __HIP_MEMORY_SCOPE_AGENT);
      if (s == CH - 1) {
        hstate[b*512 + w*64 + j0] = h0;
        hstate[b*512 + w*64 + j1] = h1;
      }
    } else if (t < 256 && (t >> 5) != w) {
      unsigned long long* fslot = &xfb[(size_t)w*256 + t];
      unsigned exp = (unsigned)(s + 1);
      unsigned long long v;
      for (;;) {
        v = ld64_sc0(fslot);                       // L2 fast path
        if ((unsigned)(v >> 32) == exp) break;
        v = __hip_atomic_load(&xp64[t], __ATOMIC_RELAXED, __HIP_MEMORY_SCOPE_AGENT);
        if ((unsigned)(v >> 32) == exp) break;
      }
      // consume-then-zero: guarantees no stale false-match ever (worst case
      // a clobbered fresh tag degrades this slot to the slow path next use)
      __hip_atomic_store(fslot, 0ull, __ATOMIC_RELAXED, __HIP_MEMORY_SCOPE_WORKGROUP);
      hq[hq_swz(t)] = (unsigned)v;
    }
    BARX();   // B2: hq complete for next gemv
  }
}

// ---------------- launch ----------------
extern "C" void kernel_launch(void* const* d_in, const int* in_sizes, int n_in,
                              void* d_out, int out_size, void* d_ws, size_t ws_size,
                              hipStream_t stream) {
  const float* f0     = (const float*)d_in[0];
  const float* loud   = (const float*)d_in[1];
  const float* es     = (const float*)d_in[2];
  const float* preW   = (const float*)d_in[3];
  const float* preb   = (const float*)d_in[4];
  const float* Wih    = (const float*)d_in[5];
  const float* Whh    = (const float*)d_in[6];
  const float* b_ih   = (const float*)d_in[7];
  const float* b_hh   = (const float*)d_in[8];
  const float* postW  = (const float*)d_in[9];
  const float* postb  = (const float*)d_in[10];
  const float* harmW  = (const float*)d_in[11];
  const float* harmb  = (const float*)d_in[12];
  const float* noiseW = (const float*)d_in[13];
  const float* noiseb = (const float*)d_in[14];
  const float* hypW1  = (const float*)d_in[15];
  const float* hypb1  = (const float*)d_in[16];
  const float* Wdh    = (const float*)d_in[17];
  const float* bdh    = (const float*)d_in[18];
  const float* Wbh    = (const float*)d_in[19];
  const float* bbh    = (const float*)d_in[20];
  const float* Wdn    = (const float*)d_in[21];
  const float* bdn    = (const float*)d_in[22];
  const float* Wbn    = (const float*)d_in[23];
  const float* bbn    = (const float*)d_in[24];
  (void)in_sizes; (void)n_in; (void)out_size;

  const size_t FIXED = 15360ull*1024ull;   // ~15 MB fixed region (incl. 1MB xfast)
  int CH = 20;
  {
    const int opts[8] = {2000, 1000, 500, 400, 200, 100, 40, 20};
    for (int i = 0; i < 8; ++i) {
      size_t need = FIXED + (size_t)opts[i] * 163840ull + 65536ull;
      if (need <= ws_size) { CH = opts[i]; break; }
    }
  }
  const int NC = T_ / CH;
  const int Mc = B_ * CH;

  char* w = (char*)d_ws;
  size_t off = 0;
  auto alloc = [&](size_t bytes) -> void* {
    void* p = (void*)(w + off);
    off += (bytes + 255) & ~(size_t)255;
    return p;
  };
  float*    hE      = (float*)alloc((size_t)32*256*4);
  float*    effb    = (float*)alloc((size_t)32*256*4);
  float*    hstate  = (float*)alloc((size_t)32*512*4);
  __half*   effW    = (__half*)alloc((size_t)32*256*512*2);
  __half*   Wih16   = (__half*)alloc((size_t)1536*512*2);
  __half*   postW16 = (__half*)alloc((size_t)512*512*2);
  uint4*    Wp      = (uint4*)alloc((size_t)8*32*384*16 + 4096);
  unsigned long long* xch64 = (unsigned long long*)alloc((size_t)2*32*256*8);
  unsigned long long* xfast = (unsigned long long*)alloc((size_t)2*32*8*256*8);
  __half*   xpre    = (__half*)alloc((size_t)Mc*512*2);
  __half*   gibuf   = (__half*)alloc((size_t)Mc*1536*2);
  __half*   ysbuf   = (__half*)alloc((size_t)Mc*512*2);
  __half*   postc   = xpre;   // xpre dead after gi GEMM

  hyper1<<<32, 256, 0, stream>>>(es, hypW1, hypb1, hE);
  hyper2<<<32, 256, 0, stream>>>(hE, Wbh, bbh, harmb, Wbn, bbn, noiseb, effb);
  hyper3<<<200, 256, 0, stream>>>(hE, Wdh, bdh, harmW, effW, 0);
  hyper3<<<130, 256, 0, stream>>>(hE, Wdn, bdn, noiseW, effW, NH_);
  cvt_f16<<<(1536*512)/256, 256, 0, stream>>>(Wih, Wih16, 1536*512);
  cvt_f16<<<(512*512)/256, 256, 0, stream>>>(postW, postW16, 512*512);
  pack_whh4<<<384, 256, 0, stream>>>(Whh, Wp);

  for (int c = 0; c < NC; ++c) {
    int c0 = c * CH;
    pre_kernel<<<dim3(CH*2, 32), 256, 0, stream>>>(f0, loud, preW, preb, xpre, CH, c0);
    gemm_nt<0><<<dim3(Mc/128, 12), 256, 0, stream>>>(xpre, Wih16, gibuf, b_ih, 1536);
    gru_scan8<<<256, 512, 0, stream>>>(Wp, gibuf, b_hh, ysbuf, hstate, xch64, xfast,
                                       CH, c == 0 ? 1 : 0);
    gemm_nt<1><<<dim3(Mc/128, 4), 256, 0, stream>>>(ysbuf, postW16, postc, postb, 512);
    heads_gemm<<<dim3((CH+127)/128, 2, 32), 256, 0, stream>>>(postc, effW, effb,
                                                              (float*)d_out, CH, c0);
  }
}

// Round 13
// 4535.984 us; speedup vs baseline: 1.1919x; 1.0172x over previous
//
#include <hip/hip_runtime.h>
#include <hip/hip_fp16.h>
#include <stdint.h>

#define B_  32
#define T_  2000
#define H_  512
#define NH_ 100
#define NM_ 65

typedef _Float16 f16x8 __attribute__((ext_vector_type(8)));
typedef _Float16 f16x2 __attribute__((ext_vector_type(2)));
typedef float    f32x4 __attribute__((ext_vector_type(4)));

typedef __attribute__((address_space(3))) void lds_void_t;
typedef __attribute__((address_space(1))) void glb_void_t;

__device__ __forceinline__ void gload_lds16(const void* g, void* l) {
  __builtin_amdgcn_global_load_lds((const glb_void_t*)g, (lds_void_t*)l, 16, 0, 0);
}

__device__ __forceinline__ float sigmoidf_(float x) {
  float e = __builtin_amdgcn_exp2f(-x * 1.44269504f);
  return __builtin_amdgcn_rcpf(1.0f + e);
}
__device__ __forceinline__ float tanhf_(float x) {
  float e = __builtin_amdgcn_exp2f(x * 2.88539008f);
  return 1.0f - 2.0f * __builtin_amdgcn_rcpf(e + 1.0f);
}
__device__ __forceinline__ float dot2(unsigned w, unsigned h, float acc) {
  return __builtin_amdgcn_fdot2(__builtin_bit_cast(f16x2, w),
                                __builtin_bit_cast(f16x2, h), acc, false);
}
__device__ __forceinline__ unsigned pack2(float a, float b) {
  __half2 h = __floats2half2_rn(a, b);
  return __builtin_bit_cast(unsigned, h);
}
__device__ __forceinline__ float hsel(unsigned w, int hi) {
  __half2 h2 = __builtin_bit_cast(__half2, w);
  return hi ? __high2float(h2) : __low2float(h2);
}
__device__ __forceinline__ int hq_swz(int i) {
  int cs = i >> 5, kk = (i >> 2) & 7;
  return cs*32 + ((kk ^ cs) << 2) + (i & 3);
}

// ---------------- hypernetwork ----------------
__global__ void hyper1(const float* __restrict__ es, const float* __restrict__ W1,
                       const float* __restrict__ b1, float* __restrict__ hE) {
  int b = blockIdx.x, o = threadIdx.x;   // 32 x 256
  float a = b1[o];
  #pragma unroll
  for (int c = 0; c < 16; ++c) a += es[b*16 + c] * W1[o*16 + c];
  hE[b*256 + o] = fmaxf(a, 0.f);
}

__global__ void hyper2(const float* __restrict__ hE,
                       const float* __restrict__ Wbh, const float* __restrict__ bbh,
                       const float* __restrict__ harmb,
                       const float* __restrict__ Wbn, const float* __restrict__ bbn,
                       const float* __restrict__ noiseb, float* __restrict__ effb) {
  int b = blockIdx.x, o = threadIdx.x;
  if (o < NH_) {
    float a = bbh[o] + harmb[o];
    for (int c = 0; c < 256; ++c) a += hE[b*256 + c] * Wbh[o*256 + c];
    effb[b*256 + o] = a;
  } else if (o < NH_ + NM_) {
    int q = o - NH_;
    float a = bbn[q] + noiseb[q];
    for (int c = 0; c < 256; ++c) a += hE[b*256 + c] * Wbn[q*256 + c];
    effb[b*256 + o] = a;
  }
}

// effW[b][o_base+o][h] = baseW[o*512+h] + bd[row] + sum_c Wd[row][c]*hE[b][c]
__global__ __launch_bounds__(256) void hyper3(
    const float* __restrict__ hE, const float* __restrict__ Wd,
    const float* __restrict__ bd, const float* __restrict__ baseW,
    __half* __restrict__ effW, int o_base) {
  __shared__ float wl[256*33];
  __shared__ float hEl[32*256];
  int tid = threadIdx.x;
  int row0 = blockIdx.x * 256;
  #pragma unroll
  for (int i = 0; i < 32; ++i) hEl[i*256 + tid] = hE[i*256 + tid];
  float acc[32];
  #pragma unroll
  for (int b = 0; b < 32; ++b) acc[b] = 0.f;
  for (int cc = 0; cc < 256; cc += 32) {
    __syncthreads();
    #pragma unroll
    for (int i = 0; i < 32; ++i) {
      int idx = i*256 + tid;
      int r = idx >> 5, c = idx & 31;
      wl[r*33 + c] = Wd[(size_t)(row0 + r)*256 + cc + c];
    }
    __syncthreads();
    #pragma unroll
    for (int c = 0; c < 32; ++c) {
      float w = wl[tid*33 + c];
      #pragma unroll
      for (int b = 0; b < 32; ++b) acc[b] += w * hEl[b*256 + cc + c];
    }
  }
  int row = row0 + tid;
  int o = row >> 9, h = row & 511;
  float base = baseW[row] + bd[row];
  #pragma unroll
  for (int b = 0; b < 32; ++b) {
    effW[((size_t)b*256 + o_base + o)*512 + h] = (__half)(acc[b] + base);
  }
}

// ---------------- converts ----------------
__global__ void cvt_f16(const float* __restrict__ in, __half* __restrict__ out, int n) {
  int i = blockIdx.x*256 + threadIdx.x;
  if (i < n) out[i] = (__half)in[i];
}

__global__ void zero_claims(unsigned* __restrict__ c) { c[threadIdx.x] = 0u; }

// Wp4[(w*32 + k)*384 + t]: thread t = rq*8+cs owns 4 rows x 64 cols.
// k = j*8 + kk: row = (rq>>4)*512 + w*64 + (rq&15)*4 + j, cols = cs*64 + kk*8 ..+8
__global__ void pack_whh4(const float* __restrict__ Whh, uint4* __restrict__ Wp) {
  int idx = blockIdx.x*256 + threadIdx.x;    // 8*32*384 = 98304
  int t = idx % 384;
  int k = (idx / 384) & 31;
  int w = idx / (384*32);
  int rq = t >> 3, cs = t & 7;
  int j = k >> 3, kk = k & 7;
  int row = (rq >> 4)*512 + w*64 + (rq & 15)*4 + j;
  int col0 = cs*64 + kk*8;
  const float* src = Whh + (size_t)row*512 + col0;
  uint4 o;
  o.x = pack2(src[0], src[1]);
  o.y = pack2(src[2], src[3]);
  o.z = pack2(src[4], src[5]);
  o.w = pack2(src[6], src[7]);
  Wp[idx] = o;
}

// ---------------- pre layer (per chunk) ----------------
__global__ void pre_kernel(const float* __restrict__ f0, const float* __restrict__ loud,
                           const float* __restrict__ preW, const float* __restrict__ preb,
                           __half* __restrict__ xpre, int CH, int c0) {
  int b = blockIdx.y;
  int idx = blockIdx.x*256 + threadIdx.x;    // CH*512
  int t = idx >> 9, h = idx & 511;
  int mg = b*T_ + c0 + t;
  float v = f0[mg]*preW[h*2+0] + loud[mg]*preW[h*2+1] + preb[h];
  v = v >= 0.f ? v : 0.01f*v;
  xpre[((size_t)b*CH + t)*512 + h] = (__half)v;
}

// ---------------- trunk GEMM (NT, K=512, 128x128 tile, f16 MFMA) ----------------
template<int ACT>
__global__ __launch_bounds__(256) void gemm_nt(
    const __half* __restrict__ A, const __half* __restrict__ B,
    __half* __restrict__ C, const float* __restrict__ bias, int N) {
  constexpr int K = 512;
  __shared__ __align__(16) __half As[128*64];
  __shared__ __align__(16) __half Bs[128*64];
  int tid = threadIdx.x;
  int bx = blockIdx.x, by = blockIdx.y;
  const __half* Ab = A + (size_t)bx*128*K;
  const __half* Bb = B + (size_t)by*128*K;
  f32x4 acc[4][4] = {};
  int lane = tid & 63;
  int wv = tid >> 6, wr = wv >> 1, wc = wv & 1;
  int lr = lane & 15, lk = lane >> 4;

  for (int kt = 0; kt < K/64; ++kt) {
    #pragma unroll
    for (int j = 0; j < 4; ++j) {
      int idx = j*256 + tid;
      int row = idx >> 3, seg = idx & 7;
      const __half* gpA = Ab + (size_t)row*K + kt*64 + seg*8;
      const __half* gpB = Bb + (size_t)row*K + kt*64 + seg*8;
      __half* lpA = As + (size_t)(j*256 + (tid & ~63))*8;
      __half* lpB = Bs + (size_t)(j*256 + (tid & ~63))*8;
      gload_lds16(gpA, lpA);
      gload_lds16(gpB, lpB);
    }
    __syncthreads();
    #pragma unroll
    for (int ks = 0; ks < 2; ++ks) {
      f16x8 af[4], bf[4];
      #pragma unroll
      for (int i = 0; i < 4; ++i)
        af[i] = *(const f16x8*)(As + (wr*64 + i*16 + lr)*64 + ks*32 + lk*8);
      #pragma unroll
      for (int j2 = 0; j2 < 4; ++j2)
        bf[j2] = *(const f16x8*)(Bs + (wc*64 + j2*16 + lr)*64 + ks*32 + lk*8);
      #pragma unroll
      for (int i = 0; i < 4; ++i)
        #pragma unroll
        for (int j2 = 0; j2 < 4; ++j2)
          acc[i][j2] = __builtin_amdgcn_mfma_f32_16x16x32_f16(af[i], bf[j2], acc[i][j2], 0, 0, 0);
    }
    __syncthreads();
  }

  #pragma unroll
  for (int j2 = 0; j2 < 4; ++j2) {
    int col = by*128 + wc*64 + j2*16 + lr;
    float bv = bias[col];
    #pragma unroll
    for (int i = 0; i < 4; ++i) {
      int row0 = bx*128 + wr*64 + i*16 + lk*4;
      #pragma unroll
      for (int r = 0; r < 4; ++r) {
        float v = acc[i][j2][r] + bv;
        if (ACT == 1) v = v >= 0.f ? v : 0.01f*v;
        C[(size_t)(row0 + r)*N + col] = (__half)v;
      }
    }
  }
}

// ---------------- heads GEMM: per-batch modulated weights, sigmoid, fp32 out ----------------
__global__ __launch_bounds__(256) void heads_gemm(
    const __half* __restrict__ Apc, const __half* __restrict__ effW,
    const float* __restrict__ effb, float* __restrict__ out, int CH, int c0) {
  constexpr int K = 512;
  __shared__ __align__(16) __half As[128*64];
  __shared__ __align__(16) __half Bs[128*64];
  int tid = threadIdx.x;
  int bx = blockIdx.x, by = blockIdx.y, b = blockIdx.z;
  const __half* Ab = Apc + (size_t)b*CH*K;
  const __half* Bb = effW + ((size_t)b*256 + (size_t)by*128)*K;
  f32x4 acc[4][4] = {};
  int lane = tid & 63;
  int wv = tid >> 6, wr = wv >> 1, wc = wv & 1;
  int lr = lane & 15, lk = lane >> 4;

  for (int kt = 0; kt < K/64; ++kt) {
    #pragma unroll
    for (int j = 0; j < 4; ++j) {
      int idx = j*256 + tid;
      int row = idx >> 3, seg = idx & 7;
      int ar = bx*128 + row; if (ar > CH-1) ar = CH-1;
      const __half* gpA = Ab + (size_t)ar*K + kt*64 + seg*8;
      const __half* gpB = Bb + (size_t)row*K + kt*64 + seg*8;
      __half* lpA = As + (size_t)(j*256 + (tid & ~63))*8;
      __half* lpB = Bs + (size_t)(j*256 + (tid & ~63))*8;
      gload_lds16(gpA, lpA);
      gload_lds16(gpB, lpB);
    }
    __syncthreads();
    #pragma unroll
    for (int ks = 0; ks < 2; ++ks) {
      f16x8 af[4], bf[4];
      #pragma unroll
      for (int i = 0; i < 4; ++i)
        af[i] = *(const f16x8*)(As + (wr*64 + i*16 + lr)*64 + ks*32 + lk*8);
      #pragma unroll
      for (int j2 = 0; j2 < 4; ++j2)
        bf[j2] = *(const f16x8*)(Bs + (wc*64 + j2*16 + lr)*64 + ks*32 + lk*8);
      #pragma unroll
      for (int i = 0; i < 4; ++i)
        #pragma unroll
        for (int j2 = 0; j2 < 4; ++j2)
          acc[i][j2] = __builtin_amdgcn_mfma_f32_16x16x32_f16(af[i], bf[j2], acc[i][j2], 0, 0, 0);
    }
    __syncthreads();
  }

  #pragma unroll
  for (int j2 = 0; j2 < 4; ++j2) {
    int o = by*128 + wc*64 + j2*16 + lr;
    if (o < NH_ + NM_) {
      float bv = effb[b*256 + o];
      #pragma unroll
      for (int i = 0; i < 4; ++i) {
        #pragma unroll
        for (int r = 0; r < 4; ++r) {
          int trow = bx*128 + wr*64 + i*16 + lk*4 + r;
          if (trow < CH) {
            int tg = c0 + trow;
            float v = sigmoidf_(acc[i][j2][r] + bv);
            if (o < NH_)
              out[((size_t)b*T_ + tg)*NH_ + o] = v;
            else
              out[(size_t)B_*T_*NH_ + ((size_t)b*T_ + tg)*NM_ + (o - NH_)] = v;
          }
        }
      }
    }
  }
}

// ---------------- GRU scan: r9 structure + tear-proof XCD-local fast exchange ----
// r9 base (verified 1.80ms/dispatch). The ~3400cy/step wait = agent-scope (MALL)
// publish->detect. Fast path through the per-XCD shared L2 (~300cy), made SAFE:
// (1) 82KB LDS pad -> 1 WG/CU -> 256 WGs on 256 CUs -> 32/XCD; XCC_ID [m09]
//     CAS-claim (HW_ID-CU hint, wrap-scan bijection) -> batch's 8 WGs co-XCD.
// (2) tear-proof: publisher stores DATA dword, vmcnt(0)-acks it in L2, THEN
//     stores TAG dword. Reader's dwordx2 sc0 poll: tag match => data present
//     (4B stores cannot tear; r12's torn volatile u64 store is eliminated).
// (3) tags chunk-unique (tb+s+1): no cross-chunk false match via stale MALL
//     copies. Agent-scope slot stays authoritative; reader alternates fast/slow
//     -> correct for ANY placement (G16); replay reuse benign (deterministic).
#define LOADW(k) { const uint4* p = Wp + ((size_t)(w*32 + (k)))*384 + t; \
  asm volatile("global_load_dwordx4 %0, %1, off" : "=v"(wq_##k) : "v"(p) : "memory"); }

#define DOT4(k, hv, A) { \
  A = dot2(wq_##k.x, hv.x, A); A = dot2(wq_##k.y, hv.y, A); \
  A = dot2(wq_##k.z, hv.z, A); A = dot2(wq_##k.w, hv.w, A); }

#define BARX() do { asm volatile("s_waitcnt lgkmcnt(0)\n\ts_barrier" ::: "memory"); \
                    __builtin_amdgcn_sched_barrier(0); } while (0)

__global__ __launch_bounds__(512) __attribute__((amdgpu_waves_per_eu(2, 4)))
void gru_scan8(
    const uint4* __restrict__ Wp, const __half* __restrict__ gi_c,
    const float* __restrict__ bhh, __half* __restrict__ ys_c,
    float* __restrict__ hstate, unsigned long long* __restrict__ xch64,
    unsigned long long* __restrict__ xfl2, unsigned* __restrict__ claim,
    int CH, int first, int tb) {
  int t = threadIdx.x;

  __shared__ unsigned pad[20480];   // 80KB: forces 1 WG/CU (kept live below)
  __shared__ int role_sh;
  if (first > 1) pad[t] = t;        // never taken (first is 0/1) — keeps pad

  if (t == 0) {
    unsigned xcc, hwid;
    asm volatile("s_getreg_b32 %0, hwreg(HW_REG_XCC_ID)" : "=s"(xcc));
    asm volatile("s_getreg_b32 %0, hwreg(HW_REG_HW_ID)" : "=s"(hwid));
    int base = (int)(xcc & 7) * 32;
    int cu = (int)((hwid >> 8) & 0xF) | (int)(((hwid >> 12) & 1) << 4);
    int role = 0;
    for (int i = 0; i < 288; ++i) {
      int sidx = (i < 32) ? base + ((cu + i) & 31) : (base + i) & 255;
      if (atomicCAS(&claim[sidx], 0u, 1u) == 0u) { role = sidx; break; }
    }
    role_sh = role;
  }
  __syncthreads();
  int role = role_sh;
  int b = role >> 3;          // batch (8 co-XCD producers when dispatch uniform)
  int w = role & 7;           // unit-block 0..7
  int rq = t >> 3, cs = t & 7;
  bool wact = (t < 384);      // waves 0-5 hold weights
  bool comb = (t >= 384 && t < 416);   // wave 6 lower half: combine
  int tc = t - 384;           // combine lane (units 2tc, 2tc+1)

  __shared__ __align__(16) unsigned hq[256];   // h packed f16x2, swizzled (hq_swz)
  __shared__ float part[192];                  // fully-reduced gate partials [g*64+u]
  __shared__ float gil[192];                   // gi slices for combine

  uint4 wq_0{},wq_1{},wq_2{},wq_3{},wq_4{},wq_5{},wq_6{},wq_7{},
        wq_8{},wq_9{},wq_10{},wq_11{},wq_12{},wq_13{},wq_14{},wq_15{},
        wq_16{},wq_17{},wq_18{},wq_19{},wq_20{},wq_21{},wq_22{},wq_23{},
        wq_24{},wq_25{},wq_26{},wq_27{},wq_28{},wq_29{},wq_30{},wq_31{};
  if (wact) {
    LOADW(0)  LOADW(1)  LOADW(2)  LOADW(3)  LOADW(4)  LOADW(5)  LOADW(6)  LOADW(7)
    LOADW(8)  LOADW(9)  LOADW(10) LOADW(11) LOADW(12) LOADW(13) LOADW(14) LOADW(15)
    LOADW(16) LOADW(17) LOADW(18) LOADW(19) LOADW(20) LOADW(21) LOADW(22) LOADW(23)
    LOADW(24) LOADW(25) LOADW(26) LOADW(27) LOADW(28) LOADW(29) LOADW(30) LOADW(31)
  }
  asm volatile("s_waitcnt vmcnt(0)" ::: "memory");
  __builtin_amdgcn_sched_barrier(0);

  // combine-wave biases (tc handles units 2tc, 2tc+1)
  float br0=0.f,br1=0.f,bz0=0.f,bz1=0.f,bn0=0.f,bn1=0.f;
  if (comb) {
    int u0 = w*64 + 2*tc;
    br0 = bhh[u0];        br1 = bhh[u0+1];
    bz0 = bhh[512+u0];    bz1 = bhh[512+u0+1];
    bn0 = bhh[1024+u0];   bn1 = bhh[1024+u0+1];
  }

  if (t < 256) {
    unsigned hv0 = first ? 0u : pack2(hstate[b*512 + 2*t], hstate[b*512 + 2*t + 1]);
    hq[hq_swz(t)] = hv0;
  }
  __syncthreads();

  const __half* gib = gi_c + (size_t)b*CH*1536;
  __half* ysb = ys_c + (size_t)b*CH*512;
  const uint4* hq4 = (const uint4*)hq;
  int hb = cs*8;

  // gi prefetch: giv_cur holds step-s value; load s+1 at loop top
  float giv_cur = 0.f, giv_next = 0.f;
  if (t < 192) giv_cur = (float)gib[(t >> 6)*512 + w*64 + (t & 63)];

  for (int s = 0; s < CH; ++s) {
    int p = s & 1;
    unsigned long long* xp64 = xch64 + ((size_t)p*32 + b)*256;
    unsigned long long* xf   = xfl2  + ((size_t)p*32 + b)*256;
    unsigned tag = (unsigned)(tb + s + 1);

    if (t < 192 && s + 1 < CH)
      giv_next = (float)gib[(size_t)(s+1)*1536 + (t >> 6)*512 + w*64 + (t & 63)];

    if (wact) {
      uint4 hv0_ = hq4[hb + (0 ^ cs)];
      uint4 hv1_ = hq4[hb + (1 ^ cs)];
      uint4 hv2_ = hq4[hb + (2 ^ cs)];
      uint4 hv3_ = hq4[hb + (3 ^ cs)];
      uint4 hv4_ = hq4[hb + (4 ^ cs)];
      uint4 hv5_ = hq4[hb + (5 ^ cs)];
      uint4 hv6_ = hq4[hb + (6 ^ cs)];
      uint4 hv7_ = hq4[hb + (7 ^ cs)];
      float a0 = 0.f, a1 = 0.f, a2 = 0.f, a3 = 0.f;
      DOT4(0,hv0_,a0)  DOT4(8,hv0_,a1)  DOT4(16,hv0_,a2) DOT4(24,hv0_,a3)
      DOT4(1,hv1_,a0)  DOT4(9,hv1_,a1)  DOT4(17,hv1_,a2) DOT4(25,hv1_,a3)
      DOT4(2,hv2_,a0)  DOT4(10,hv2_,a1) DOT4(18,hv2_,a2) DOT4(26,hv2_,a3)
      DOT4(3,hv3_,a0)  DOT4(11,hv3_,a1) DOT4(19,hv3_,a2) DOT4(27,hv3_,a3)
      DOT4(4,hv4_,a0)  DOT4(12,hv4_,a1) DOT4(20,hv4_,a2) DOT4(28,hv4_,a3)
      DOT4(5,hv5_,a0)  DOT4(13,hv5_,a1) DOT4(21,hv5_,a2) DOT4(29,hv5_,a3)
      DOT4(6,hv6_,a0)  DOT4(14,hv6_,a1) DOT4(22,hv6_,a2) DOT4(30,hv6_,a3)
      DOT4(7,hv7_,a0)  DOT4(15,hv7_,a1) DOT4(23,hv7_,a2) DOT4(31,hv7_,a3)
      // in-wave 8-way column reduce (cs lanes adjacent: xor 1,2,4 stay in group)
      a0 += __shfl_xor(a0, 1); a0 += __shfl_xor(a0, 2); a0 += __shfl_xor(a0, 4);
      a1 += __shfl_xor(a1, 1); a1 += __shfl_xor(a1, 2); a1 += __shfl_xor(a1, 4);
      a2 += __shfl_xor(a2, 1); a2 += __shfl_xor(a2, 2); a2 += __shfl_xor(a2, 4);
      a3 += __shfl_xor(a3, 1); a3 += __shfl_xor(a3, 2); a3 += __shfl_xor(a3, 4);
      if (cs < 4) {
        float v = (cs == 0) ? a0 : (cs == 1) ? a1 : (cs == 2) ? a2 : a3;
        part[(rq << 2) + cs] = v;
      }
      if (t < 192) gil[t] = giv_cur;
    }
    giv_cur = giv_next;
    BARX();   // B1: part + gil visible

    if (comb) {
      int j0 = 2*tc, j1 = 2*tc + 1;
      float r0 = sigmoidf_(gil[j0] + part[j0] + br0);
      float r1 = sigmoidf_(gil[j1] + part[j1] + br1);
      float z0 = sigmoidf_(gil[64+j0] + part[64+j0] + bz0);
      float z1 = sigmoidf_(gil[64+j1] + part[64+j1] + bz1);
      float n0 = tanhf_(gil[128+j0] + r0*(part[128+j0] + bn0));
      float n1 = tanhf_(gil[128+j1] + r1*(part[128+j1] + bn1));
      int gidx = w*32 + tc;
      int hidx = hq_swz(gidx);
      unsigned hold = hq[hidx];
      float h0 = (1.f - z0)*n0 + z0*hsel(hold, 0);
      float h1 = (1.f - z1)*n1 + z1*hsel(hold, 1);
      unsigned hv = pack2(h0, h1);
      unsigned* fsl = (unsigned*)&xf[gidx];
      // fast path: DATA dword first...
      asm volatile("global_store_dword %0, %1, off" :: "v"(fsl), "v"(hv) : "memory");
      *(unsigned*)&ysb[(size_t)s*512 + w*64 + j0] = hv;           // ys (background)
      asm volatile("s_waitcnt vmcnt(0)" ::: "memory");            // data acked in L2
      // ...THEN tag dword: any tag observer sees the data (no tearing possible)
      asm volatile("global_store_dword %0, %1, off" :: "v"(fsl + 1), "v"(tag) : "memory");
      unsigned long long tv = ((unsigned long long)tag << 32) | (unsigned long long)hv;
      __hip_atomic_store(&xp64[gidx], tv,
                         __ATOMIC_RELAXED, __HIP_MEMORY_SCOPE_AGENT);  // authoritative
      hq[hidx] = hv;                                              // own slice -> LDS
      if (s == CH - 1) {
        hstate[b*512 + w*64 + j0] = h0;
        hstate[b*512 + w*64 + j1] = h1;
      }
    } else if (t < 256 && (t >> 5) != w) {
      unsigned long long v;
      int it = 0;
      for (;;) {
        unsigned long long fv;
        asm volatile("global_load_dwordx2 %0, %1, off sc0\n\ts_waitcnt vmcnt(0)"
                     : "=v"(fv) : "v"(&xf[t]) : "memory");
        if ((unsigned)(fv >> 32) == tag) { v = fv; break; }
        if (it++ >= 1) {
          v = __hip_atomic_load(&xp64[t], __ATOMIC_RELAXED, __HIP_MEMORY_SCOPE_AGENT);
          if ((unsigned)(v >> 32) == tag) break;
        }
      }
      hq[hq_swz(t)] = (unsigned)v;
    }
    BARX();   // B2: hq complete for next gemv
  }
}

// ---------------- launch ----------------
extern "C" void kernel_launch(void* const* d_in, const int* in_sizes, int n_in,
                              void* d_out, int out_size, void* d_ws, size_t ws_size,
                              hipStream_t stream) {
  const float* f0     = (const float*)d_in[0];
  const float* loud   = (const float*)d_in[1];
  const float* es     = (const float*)d_in[2];
  const float* preW   = (const float*)d_in[3];
  const float* preb   = (const float*)d_in[4];
  const float* Wih    = (const float*)d_in[5];
  const float* Whh    = (const float*)d_in[6];
  const float* b_ih   = (const float*)d_in[7];
  const float* b_hh   = (const float*)d_in[8];
  const float* postW  = (const float*)d_in[9];
  const float* postb  = (const float*)d_in[10];
  const float* harmW  = (const float*)d_in[11];
  const float* harmb  = (const float*)d_in[12];
  const float* noiseW = (const float*)d_in[13];
  const float* noiseb = (const float*)d_in[14];
  const float* hypW1  = (const float*)d_in[15];
  const float* hypb1  = (const float*)d_in[16];
  const float* Wdh    = (const float*)d_in[17];
  const float* bdh    = (const float*)d_in[18];
  const float* Wbh    = (const float*)d_in[19];
  const float* bbh    = (const float*)d_in[20];
  const float* Wdn    = (const float*)d_in[21];
  const float* bdn    = (const float*)d_in[22];
  const float* Wbn    = (const float*)d_in[23];
  const float* bbn    = (const float*)d_in[24];
  (void)in_sizes; (void)n_in; (void)out_size;

  const size_t FIXED = 15360ull*1024ull;   // ~15 MB fixed region
  int CH = 20;
  {
    const int opts[8] = {2000, 1000, 500, 400, 200, 100, 40, 20};
    for (int i = 0; i < 8; ++i) {
      size_t need = FIXED + (size_t)opts[i] * 163840ull + 65536ull;
      if (need <= ws_size) { CH = opts[i]; break; }
    }
  }
  const int NC = T_ / CH;
  const int Mc = B_ * CH;

  char* w = (char*)d_ws;
  size_t off = 0;
  auto alloc = [&](size_t bytes) -> void* {
    void* p = (void*)(w + off);
    off += (bytes + 255) & ~(size_t)255;
    return p;
  };
  float*    hE      = (float*)alloc((size_t)32*256*4);
  float*    effb    = (float*)alloc((size_t)32*256*4);
  float*    hstate  = (float*)alloc((size_t)32*512*4);
  __half*   effW    = (__half*)alloc((size_t)32*256*512*2);
  __half*   Wih16   = (__half*)alloc((size_t)1536*512*2);
  __half*   postW16 = (__half*)alloc((size_t)512*512*2);
  uint4*    Wp      = (uint4*)alloc((size_t)8*32*384*16 + 4096);
  unsigned long long* xch64 = (unsigned long long*)alloc((size_t)2*32*256*8);
  unsigned long long* xfl2  = (unsigned long long*)alloc((size_t)2*32*256*8);
  unsigned* claim   = (unsigned*)alloc((size_t)256*4);
  __half*   xpre    = (__half*)alloc((size_t)Mc*512*2);
  __half*   gibuf   = (__half*)alloc((size_t)Mc*1536*2);
  __half*   ysbuf   = (__half*)alloc((size_t)Mc*512*2);
  __half*   postc   = xpre;   // xpre dead after gi GEMM

  hyper1<<<32, 256, 0, stream>>>(es, hypW1, hypb1, hE);
  hyper2<<<32, 256, 0, stream>>>(hE, Wbh, bbh, harmb, Wbn, bbn, noiseb, effb);
  hyper3<<<200, 256, 0, stream>>>(hE, Wdh, bdh, harmW, effW, 0);
  hyper3<<<130, 256, 0, stream>>>(hE, Wdn, bdn, noiseW, effW, NH_);
  cvt_f16<<<(1536*512)/256, 256, 0, stream>>>(Wih, Wih16, 1536*512);
  cvt_f16<<<(512*512)/256, 256, 0, stream>>>(postW, postW16, 512*512);
  pack_whh4<<<384, 256, 0, stream>>>(Whh, Wp);

  for (int c = 0; c < NC; ++c) {
    int c0 = c * CH;
    pre_kernel<<<dim3(CH*2, 32), 256, 0, stream>>>(f0, loud, preW, preb, xpre, CH, c0);
    gemm_nt<0><<<dim3(Mc/128, 12), 256, 0, stream>>>(xpre, Wih16, gibuf, b_ih, 1536);
    zero_claims<<<1, 256, 0, stream>>>(claim);
    gru_scan8<<<256, 512, 0, stream>>>(Wp, gibuf, b_hh, ysbuf, hstate, xch64, xfl2,
                                       claim, CH, c == 0 ? 1 : 0, c*CH);
    gemm_nt<1><<<dim3(Mc/128, 4), 256, 0, stream>>>(ysbuf, postW16, postc, postb, 512);
    heads_gemm<<<dim3((CH+127)/128, 2, 32), 256, 0, stream>>>(postc, effW, effb,
                                                              (float*)d_out, CH, c0);
  }
}

// Round 14
// 4496.809 us; speedup vs baseline: 1.2023x; 1.0087x over previous
//
#include <hip/hip_runtime.h>
#include <hip/hip_fp16.h>
#include <stdint.h>

#define B_  32
#define T_  2000
#define H_  512
#define NH_ 100
#define NM_ 65

typedef _Float16 f16x8 __attribute__((ext_vector_type(8)));
typedef _Float16 f16x2 __attribute__((ext_vector_type(2)));
typedef float    f32x4 __attribute__((ext_vector_type(4)));

typedef __attribute__((address_space(3))) void lds_void_t;
typedef __attribute__((address_space(1))) void glb_void_t;

__device__ __forceinline__ void gload_lds16(const void* g, void* l) {
  __builtin_amdgcn_global_load_lds((const glb_void_t*)g, (lds_void_t*)l, 16, 0, 0);
}

__device__ __forceinline__ float sigmoidf_(float x) {
  float e = __builtin_amdgcn_exp2f(-x * 1.44269504f);
  return __builtin_amdgcn_rcpf(1.0f + e);
}
__device__ __forceinline__ float tanhf_(float x) {
  float e = __builtin_amdgcn_exp2f(x * 2.88539008f);
  return 1.0f - 2.0f * __builtin_amdgcn_rcpf(e + 1.0f);
}
__device__ __forceinline__ float dot2(unsigned w, unsigned h, float acc) {
  return __builtin_amdgcn_fdot2(__builtin_bit_cast(f16x2, w),
                                __builtin_bit_cast(f16x2, h), acc, false);
}
__device__ __forceinline__ unsigned pack2(float a, float b) {
  __half2 h = __floats2half2_rn(a, b);
  return __builtin_bit_cast(unsigned, h);
}
__device__ __forceinline__ float hsel(unsigned w, int hi) {
  __half2 h2 = __builtin_bit_cast(__half2, w);
  return hi ? __high2float(h2) : __low2float(h2);
}
__device__ __forceinline__ int hq_swz(int i) {
  int cs = i >> 5, kk = (i >> 2) & 7;
  return cs*32 + ((kk ^ cs) << 2) + (i & 3);
}

// ---------------- hypernetwork ----------------
__global__ void hyper1(const float* __restrict__ es, const float* __restrict__ W1,
                       const float* __restrict__ b1, float* __restrict__ hE) {
  int b = blockIdx.x, o = threadIdx.x;   // 32 x 256
  float a = b1[o];
  #pragma unroll
  for (int c = 0; c < 16; ++c) a += es[b*16 + c] * W1[o*16 + c];
  hE[b*256 + o] = fmaxf(a, 0.f);
}

__global__ void hyper2(const float* __restrict__ hE,
                       const float* __restrict__ Wbh, const float* __restrict__ bbh,
                       const float* __restrict__ harmb,
                       const float* __restrict__ Wbn, const float* __restrict__ bbn,
                       const float* __restrict__ noiseb, float* __restrict__ effb) {
  int b = blockIdx.x, o = threadIdx.x;
  if (o < NH_) {
    float a = bbh[o] + harmb[o];
    for (int c = 0; c < 256; ++c) a += hE[b*256 + c] * Wbh[o*256 + c];
    effb[b*256 + o] = a;
  } else if (o < NH_ + NM_) {
    int q = o - NH_;
    float a = bbn[q] + noiseb[q];
    for (int c = 0; c < 256; ++c) a += hE[b*256 + c] * Wbn[q*256 + c];
    effb[b*256 + o] = a;
  }
}

// effW[b][o_base+o][h] = baseW[o*512+h] + bd[row] + sum_c Wd[row][c]*hE[b][c]
__global__ __launch_bounds__(256) void hyper3(
    const float* __restrict__ hE, const float* __restrict__ Wd,
    const float* __restrict__ bd, const float* __restrict__ baseW,
    __half* __restrict__ effW, int o_base) {
  __shared__ float wl[256*33];
  __shared__ float hEl[32*256];
  int tid = threadIdx.x;
  int row0 = blockIdx.x * 256;
  #pragma unroll
  for (int i = 0; i < 32; ++i) hEl[i*256 + tid] = hE[i*256 + tid];
  float acc[32];
  #pragma unroll
  for (int b = 0; b < 32; ++b) acc[b] = 0.f;
  for (int cc = 0; cc < 256; cc += 32) {
    __syncthreads();
    #pragma unroll
    for (int i = 0; i < 32; ++i) {
      int idx = i*256 + tid;
      int r = idx >> 5, c = idx & 31;
      wl[r*33 + c] = Wd[(size_t)(row0 + r)*256 + cc + c];
    }
    __syncthreads();
    #pragma unroll
    for (int c = 0; c < 32; ++c) {
      float w = wl[tid*33 + c];
      #pragma unroll
      for (int b = 0; b < 32; ++b) acc[b] += w * hEl[b*256 + cc + c];
    }
  }
  int row = row0 + tid;
  int o = row >> 9, h = row & 511;
  float base = baseW[row] + bd[row];
  #pragma unroll
  for (int b = 0; b < 32; ++b) {
    effW[((size_t)b*256 + o_base + o)*512 + h] = (__half)(acc[b] + base);
  }
}

// ---------------- converts ----------------
__global__ void cvt_f16(const float* __restrict__ in, __half* __restrict__ out, int n) {
  int i = blockIdx.x*256 + threadIdx.x;
  if (i < n) out[i] = (__half)in[i];
}

// Wp4[(w*32 + k)*384 + t]: thread t = rq*8+cs owns 4 rows x 64 cols.
// k = j*8 + kk: row = (rq>>4)*512 + w*64 + (rq&15)*4 + j, cols = cs*64 + kk*8 ..+8
__global__ void pack_whh4(const float* __restrict__ Whh, uint4* __restrict__ Wp) {
  int idx = blockIdx.x*256 + threadIdx.x;    // 8*32*384 = 98304
  int t = idx % 384;
  int k = (idx / 384) & 31;
  int w = idx / (384*32);
  int rq = t >> 3, cs = t & 7;
  int j = k >> 3, kk = k & 7;
  int row = (rq >> 4)*512 + w*64 + (rq & 15)*4 + j;
  int col0 = cs*64 + kk*8;
  const float* src = Whh + (size_t)row*512 + col0;
  uint4 o;
  o.x = pack2(src[0], src[1]);
  o.y = pack2(src[2], src[3]);
  o.z = pack2(src[4], src[5]);
  o.w = pack2(src[6], src[7]);
  Wp[idx] = o;
}

// ---------------- pre layer (per chunk) ----------------
__global__ void pre_kernel(const float* __restrict__ f0, const float* __restrict__ loud,
                           const float* __restrict__ preW, const float* __restrict__ preb,
                           __half* __restrict__ xpre, int CH, int c0) {
  int b = blockIdx.y;
  int idx = blockIdx.x*256 + threadIdx.x;    // CH*512
  int t = idx >> 9, h = idx & 511;
  int mg = b*T_ + c0 + t;
  float v = f0[mg]*preW[h*2+0] + loud[mg]*preW[h*2+1] + preb[h];
  v = v >= 0.f ? v : 0.01f*v;
  xpre[((size_t)b*CH + t)*512 + h] = (__half)v;
}

// ---------------- trunk GEMM (NT, K=512, 128x128 tile, f16 MFMA) ----------------
template<int ACT>
__global__ __launch_bounds__(256) void gemm_nt(
    const __half* __restrict__ A, const __half* __restrict__ B,
    __half* __restrict__ C, const float* __restrict__ bias, int N) {
  constexpr int K = 512;
  __shared__ __align__(16) __half As[128*64];
  __shared__ __align__(16) __half Bs[128*64];
  int tid = threadIdx.x;
  int bx = blockIdx.x, by = blockIdx.y;
  const __half* Ab = A + (size_t)bx*128*K;
  const __half* Bb = B + (size_t)by*128*K;
  f32x4 acc[4][4] = {};
  int lane = tid & 63;
  int wv = tid >> 6, wr = wv >> 1, wc = wv & 1;
  int lr = lane & 15, lk = lane >> 4;

  for (int kt = 0; kt < K/64; ++kt) {
    #pragma unroll
    for (int j = 0; j < 4; ++j) {
      int idx = j*256 + tid;
      int row = idx >> 3, seg = idx & 7;
      const __half* gpA = Ab + (size_t)row*K + kt*64 + seg*8;
      const __half* gpB = Bb + (size_t)row*K + kt*64 + seg*8;
      __half* lpA = As + (size_t)(j*256 + (tid & ~63))*8;
      __half* lpB = Bs + (size_t)(j*256 + (tid & ~63))*8;
      gload_lds16(gpA, lpA);
      gload_lds16(gpB, lpB);
    }
    __syncthreads();
    #pragma unroll
    for (int ks = 0; ks < 2; ++ks) {
      f16x8 af[4], bf[4];
      #pragma unroll
      for (int i = 0; i < 4; ++i)
        af[i] = *(const f16x8*)(As + (wr*64 + i*16 + lr)*64 + ks*32 + lk*8);
      #pragma unroll
      for (int j2 = 0; j2 < 4; ++j2)
        bf[j2] = *(const f16x8*)(Bs + (wc*64 + j2*16 + lr)*64 + ks*32 + lk*8);
      #pragma unroll
      for (int i = 0; i < 4; ++i)
        #pragma unroll
        for (int j2 = 0; j2 < 4; ++j2)
          acc[i][j2] = __builtin_amdgcn_mfma_f32_16x16x32_f16(af[i], bf[j2], acc[i][j2], 0, 0, 0);
    }
    __syncthreads();
  }

  #pragma unroll
  for (int j2 = 0; j2 < 4; ++j2) {
    int col = by*128 + wc*64 + j2*16 + lr;
    float bv = bias[col];
    #pragma unroll
    for (int i = 0; i < 4; ++i) {
      int row0 = bx*128 + wr*64 + i*16 + lk*4;
      #pragma unroll
      for (int r = 0; r < 4; ++r) {
        float v = acc[i][j2][r] + bv;
        if (ACT == 1) v = v >= 0.f ? v : 0.01f*v;
        C[(size_t)(row0 + r)*N + col] = (__half)v;
      }
    }
  }
}

// ---------------- heads GEMM: per-batch modulated weights, sigmoid, fp32 out ----------------
__global__ __launch_bounds__(256) void heads_gemm(
    const __half* __restrict__ Apc, const __half* __restrict__ effW,
    const float* __restrict__ effb, float* __restrict__ out, int CH, int c0) {
  constexpr int K = 512;
  __shared__ __align__(16) __half As[128*64];
  __shared__ __align__(16) __half Bs[128*64];
  int tid = threadIdx.x;
  int bx = blockIdx.x, by = blockIdx.y, b = blockIdx.z;
  const __half* Ab = Apc + (size_t)b*CH*K;
  const __half* Bb = effW + ((size_t)b*256 + (size_t)by*128)*K;
  f32x4 acc[4][4] = {};
  int lane = tid & 63;
  int wv = tid >> 6, wr = wv >> 1, wc = wv & 1;
  int lr = lane & 15, lk = lane >> 4;

  for (int kt = 0; kt < K/64; ++kt) {
    #pragma unroll
    for (int j = 0; j < 4; ++j) {
      int idx = j*256 + tid;
      int row = idx >> 3, seg = idx & 7;
      int ar = bx*128 + row; if (ar > CH-1) ar = CH-1;
      const __half* gpA = Ab + (size_t)ar*K + kt*64 + seg*8;
      const __half* gpB = Bb + (size_t)row*K + kt*64 + seg*8;
      __half* lpA = As + (size_t)(j*256 + (tid & ~63))*8;
      __half* lpB = Bs + (size_t)(j*256 + (tid & ~63))*8;
      gload_lds16(gpA, lpA);
      gload_lds16(gpB, lpB);
    }
    __syncthreads();
    #pragma unroll
    for (int ks = 0; ks < 2; ++ks) {
      f16x8 af[4], bf[4];
      #pragma unroll
      for (int i = 0; i < 4; ++i)
        af[i] = *(const f16x8*)(As + (wr*64 + i*16 + lr)*64 + ks*32 + lk*8);
      #pragma unroll
      for (int j2 = 0; j2 < 4; ++j2)
        bf[j2] = *(const f16x8*)(Bs + (wc*64 + j2*16 + lr)*64 + ks*32 + lk*8);
      #pragma unroll
      for (int i = 0; i < 4; ++i)
        #pragma unroll
        for (int j2 = 0; j2 < 4; ++j2)
          acc[i][j2] = __builtin_amdgcn_mfma_f32_16x16x32_f16(af[i], bf[j2], acc[i][j2], 0, 0, 0);
    }
    __syncthreads();
  }

  #pragma unroll
  for (int j2 = 0; j2 < 4; ++j2) {
    int o = by*128 + wc*64 + j2*16 + lr;
    if (o < NH_ + NM_) {
      float bv = effb[b*256 + o];
      #pragma unroll
      for (int i = 0; i < 4; ++i) {
        #pragma unroll
        for (int r = 0; r < 4; ++r) {
          int trow = bx*128 + wr*64 + i*16 + lk*4 + r;
          if (trow < CH) {
            int tg = c0 + trow;
            float v = sigmoidf_(acc[i][j2][r] + bv);
            if (o < NH_)
              out[((size_t)b*T_ + tg)*NH_ + o] = v;
            else
              out[(size_t)B_*T_*NH_ + ((size_t)b*T_ + tg)*NM_ + (o - NH_)] = v;
          }
        }
      }
    }
  }
}

// ---------------- GRU scan: r9 structure + publish-first + ping-pong poll ----
// r9 base (best verified: 1.80 ms/dispatch). The scan is LATENCY-bound on the
// cross-CU publish->detect RT through the MALL (~1.1us/step); XCD-local paths
// (r11-r13) never beat it. Two surgical cuts on the detect term:
// (1) publish the agent-scope u64 FIRST in the combine (r9 queued it behind the
//     ys HBM store in the same VMEM queue);
// (2) ping-pong double-outstanding poll: two staggered sc0/sc1 loads in flight,
//     vmcnt(1)+sched_barrier(0) [rule 18] checks the older while the newer
//     flies -> sampling period halves. Loop exits with vmcnt(0) so the
//     dangling in-flight load can't corrupt a reused VGPR.
// Tag protocol unchanged (5 rounds proven): exact-match s+1 per parity slot;
// stale/poison values (>=CH-1>=19 or 0xAA) never match the first tags 1,2.
#define LOADW(k) { const uint4* p = Wp + ((size_t)(w*32 + (k)))*384 + t; \
  asm volatile("global_load_dwordx4 %0, %1, off" : "=v"(wq_##k) : "v"(p) : "memory"); }

#define DOT4(k, hv, A) { \
  A = dot2(wq_##k.x, hv.x, A); A = dot2(wq_##k.y, hv.y, A); \
  A = dot2(wq_##k.z, hv.z, A); A = dot2(wq_##k.w, hv.w, A); }

#define BARX() do { asm volatile("s_waitcnt lgkmcnt(0)\n\ts_barrier" ::: "memory"); \
                    __builtin_amdgcn_sched_barrier(0); } while (0)

__global__ __launch_bounds__(512) __attribute__((amdgpu_waves_per_eu(2, 4)))
void gru_scan8(
    const uint4* __restrict__ Wp, const __half* __restrict__ gi_c,
    const float* __restrict__ bhh, __half* __restrict__ ys_c,
    float* __restrict__ hstate, unsigned long long* __restrict__ xch64,
    int CH, int first) {
  int wg = blockIdx.x;
  int b = wg & 31;            // batch
  int w = wg >> 5;            // unit-block 0..7 (units w*64 .. +64)
  int t = threadIdx.x;
  int rq = t >> 3, cs = t & 7;
  bool wact = (t < 384);      // waves 0-5 hold weights
  bool comb = (t >= 384 && t < 416);   // wave 6 lower half: combine
  int tc = t - 384;           // combine lane (units 2tc, 2tc+1)

  __shared__ __align__(16) unsigned hq[256];   // h packed f16x2, swizzled (hq_swz)
  __shared__ float part[192];                  // fully-reduced gate partials [g*64+u]
  __shared__ float gil[192];                   // gi slices for combine

  uint4 wq_0{},wq_1{},wq_2{},wq_3{},wq_4{},wq_5{},wq_6{},wq_7{},
        wq_8{},wq_9{},wq_10{},wq_11{},wq_12{},wq_13{},wq_14{},wq_15{},
        wq_16{},wq_17{},wq_18{},wq_19{},wq_20{},wq_21{},wq_22{},wq_23{},
        wq_24{},wq_25{},wq_26{},wq_27{},wq_28{},wq_29{},wq_30{},wq_31{};
  if (wact) {
    LOADW(0)  LOADW(1)  LOADW(2)  LOADW(3)  LOADW(4)  LOADW(5)  LOADW(6)  LOADW(7)
    LOADW(8)  LOADW(9)  LOADW(10) LOADW(11) LOADW(12) LOADW(13) LOADW(14) LOADW(15)
    LOADW(16) LOADW(17) LOADW(18) LOADW(19) LOADW(20) LOADW(21) LOADW(22) LOADW(23)
    LOADW(24) LOADW(25) LOADW(26) LOADW(27) LOADW(28) LOADW(29) LOADW(30) LOADW(31)
  }
  asm volatile("s_waitcnt vmcnt(0)" ::: "memory");
  __builtin_amdgcn_sched_barrier(0);

  // combine-wave biases (tc handles units 2tc, 2tc+1)
  float br0=0.f,br1=0.f,bz0=0.f,bz1=0.f,bn0=0.f,bn1=0.f;
  if (comb) {
    int u0 = w*64 + 2*tc;
    br0 = bhh[u0];        br1 = bhh[u0+1];
    bz0 = bhh[512+u0];    bz1 = bhh[512+u0+1];
    bn0 = bhh[1024+u0];   bn1 = bhh[1024+u0+1];
  }

  if (t < 256) {
    unsigned hv0 = first ? 0u : pack2(hstate[b*512 + 2*t], hstate[b*512 + 2*t + 1]);
    hq[hq_swz(t)] = hv0;
  }
  __syncthreads();

  const __half* gib = gi_c + (size_t)b*CH*1536;
  __half* ysb = ys_c + (size_t)b*CH*512;
  const uint4* hq4 = (const uint4*)hq;
  int hb = cs*8;

  // gi prefetch: giv_cur holds step-s value; load s+1 at loop top
  float giv_cur = 0.f, giv_next = 0.f;
  if (t < 192) giv_cur = (float)gib[(t >> 6)*512 + w*64 + (t & 63)];

  for (int s = 0; s < CH; ++s) {
    int p = s & 1;
    unsigned long long* xp64 = xch64 + ((size_t)p*32 + b)*256;

    if (t < 192 && s + 1 < CH)
      giv_next = (float)gib[(size_t)(s+1)*1536 + (t >> 6)*512 + w*64 + (t & 63)];

    if (wact) {
      uint4 hv0_ = hq4[hb + (0 ^ cs)];
      uint4 hv1_ = hq4[hb + (1 ^ cs)];
      uint4 hv2_ = hq4[hb + (2 ^ cs)];
      uint4 hv3_ = hq4[hb + (3 ^ cs)];
      uint4 hv4_ = hq4[hb + (4 ^ cs)];
      uint4 hv5_ = hq4[hb + (5 ^ cs)];
      uint4 hv6_ = hq4[hb + (6 ^ cs)];
      uint4 hv7_ = hq4[hb + (7 ^ cs)];
      float a0 = 0.f, a1 = 0.f, a2 = 0.f, a3 = 0.f;
      DOT4(0,hv0_,a0)  DOT4(8,hv0_,a1)  DOT4(16,hv0_,a2) DOT4(24,hv0_,a3)
      DOT4(1,hv1_,a0)  DOT4(9,hv1_,a1)  DOT4(17,hv1_,a2) DOT4(25,hv1_,a3)
      DOT4(2,hv2_,a0)  DOT4(10,hv2_,a1) DOT4(18,hv2_,a2) DOT4(26,hv2_,a3)
      DOT4(3,hv3_,a0)  DOT4(11,hv3_,a1) DOT4(19,hv3_,a2) DOT4(27,hv3_,a3)
      DOT4(4,hv4_,a0)  DOT4(12,hv4_,a1) DOT4(20,hv4_,a2) DOT4(28,hv4_,a3)
      DOT4(5,hv5_,a0)  DOT4(13,hv5_,a1) DOT4(21,hv5_,a2) DOT4(29,hv5_,a3)
      DOT4(6,hv6_,a0)  DOT4(14,hv6_,a1) DOT4(22,hv6_,a2) DOT4(30,hv6_,a3)
      DOT4(7,hv7_,a0)  DOT4(15,hv7_,a1) DOT4(23,hv7_,a2) DOT4(31,hv7_,a3)
      // in-wave 8-way column reduce (cs lanes adjacent: xor 1,2,4 stay in group)
      a0 += __shfl_xor(a0, 1); a0 += __shfl_xor(a0, 2); a0 += __shfl_xor(a0, 4);
      a1 += __shfl_xor(a1, 1); a1 += __shfl_xor(a1, 2); a1 += __shfl_xor(a1, 4);
      a2 += __shfl_xor(a2, 1); a2 += __shfl_xor(a2, 2); a2 += __shfl_xor(a2, 4);
      a3 += __shfl_xor(a3, 1); a3 += __shfl_xor(a3, 2); a3 += __shfl_xor(a3, 4);
      if (cs < 4) {
        float v = (cs == 0) ? a0 : (cs == 1) ? a1 : (cs == 2) ? a2 : a3;
        part[(rq << 2) + cs] = v;
      }
      if (t < 192) gil[t] = giv_cur;
    }
    giv_cur = giv_next;
    BARX();   // B1: part + gil visible

    if (comb) {
      int j0 = 2*tc, j1 = 2*tc + 1;
      float r0 = sigmoidf_(gil[j0] + part[j0] + br0);
      float r1 = sigmoidf_(gil[j1] + part[j1] + br1);
      float z0 = sigmoidf_(gil[64+j0] + part[64+j0] + bz0);
      float z1 = sigmoidf_(gil[64+j1] + part[64+j1] + bz1);
      float n0 = tanhf_(gil[128+j0] + r0*(part[128+j0] + bn0));
      float n1 = tanhf_(gil[128+j1] + r1*(part[128+j1] + bn1));
      int gidx = w*32 + tc;
      int hidx = hq_swz(gidx);
      unsigned hold = hq[hidx];
      float h0 = (1.f - z0)*n0 + z0*hsel(hold, 0);
      float h1 = (1.f - z1)*n1 + z1*hsel(hold, 1);
      unsigned hv = pack2(h0, h1);
      // publish FIRST: nothing else sits ahead of it in this wave's VMEM queue
      unsigned long long tv = ((unsigned long long)(unsigned)(s + 1) << 32)
                              | (unsigned long long)hv;
      __hip_atomic_store(&xp64[gidx], tv,
                         __ATOMIC_RELAXED, __HIP_MEMORY_SCOPE_AGENT);
      hq[hidx] = hv;                                              // own slice -> LDS
      *(unsigned*)&ysb[(size_t)s*512 + w*64 + j0] = hv;           // ys (background)
      if (s == CH - 1) {
        hstate[b*512 + w*64 + j0] = h0;
        hstate[b*512 + w*64 + j1] = h1;
      }
    } else if (t < 256 && (t >> 5) != w) {
      const unsigned long long* slot = &xp64[t];
      unsigned exp = (unsigned)(s + 1);
      unsigned long long va, vb, v;
      asm volatile("global_load_dwordx2 %0, %2, off sc0 sc1\n\t"
                   "global_load_dwordx2 %1, %2, off sc0 sc1"
                   : "=v"(va), "=v"(vb) : "v"(slot) : "memory");
      for (;;) {
        asm volatile("s_waitcnt vmcnt(1)" ::: "memory");
        __builtin_amdgcn_sched_barrier(0);
        if ((unsigned)(va >> 32) == exp) { v = va; break; }
        asm volatile("global_load_dwordx2 %0, %1, off sc0 sc1"
                     : "=v"(va) : "v"(slot) : "memory");
        asm volatile("s_waitcnt vmcnt(1)" ::: "memory");
        __builtin_amdgcn_sched_barrier(0);
        if ((unsigned)(vb >> 32) == exp) { v = vb; break; }
        asm volatile("global_load_dwordx2 %0, %1, off sc0 sc1"
                     : "=v"(vb) : "v"(slot) : "memory");
      }
      asm volatile("s_waitcnt vmcnt(0)" ::: "memory");   // retire dangling load
      __builtin_amdgcn_sched_barrier(0);
      hq[hq_swz(t)] = (unsigned)v;
    }
    BARX();   // B2: hq complete for next gemv
  }
}

// ---------------- launch ----------------
extern "C" void kernel_launch(void* const* d_in, const int* in_sizes, int n_in,
                              void* d_out, int out_size, void* d_ws, size_t ws_size,
                              hipStream_t stream) {
  const float* f0     = (const float*)d_in[0];
  const float* loud   = (const float*)d_in[1];
  const float* es     = (const float*)d_in[2];
  const float* preW   = (const float*)d_in[3];
  const float* preb   = (const float*)d_in[4];
  const float* Wih    = (const float*)d_in[5];
  const float* Whh    = (const float*)d_in[6];
  const float* b_ih   = (const float*)d_in[7];
  const float* b_hh   = (const float*)d_in[8];
  const float* postW  = (const float*)d_in[9];
  const float* postb  = (const float*)d_in[10];
  const float* harmW  = (const float*)d_in[11];
  const float* harmb  = (const float*)d_in[12];
  const float* noiseW = (const float*)d_in[13];
  const float* noiseb = (const float*)d_in[14];
  const float* hypW1  = (const float*)d_in[15];
  const float* hypb1  = (const float*)d_in[16];
  const float* Wdh    = (const float*)d_in[17];
  const float* bdh    = (const float*)d_in[18];
  const float* Wbh    = (const float*)d_in[19];
  const float* bbh    = (const float*)d_in[20];
  const float* Wdn    = (const float*)d_in[21];
  const float* bdn    = (const float*)d_in[22];
  const float* Wbn    = (const float*)d_in[23];
  const float* bbn    = (const float*)d_in[24];
  (void)in_sizes; (void)n_in; (void)out_size;

  const size_t FIXED = 14336ull*1024ull;   // ~14 MB fixed region
  int CH = 20;
  {
    const int opts[8] = {2000, 1000, 500, 400, 200, 100, 40, 20};
    for (int i = 0; i < 8; ++i) {
      size_t need = FIXED + (size_t)opts[i] * 163840ull + 65536ull;
      if (need <= ws_size) { CH = opts[i]; break; }
    }
  }
  const int NC = T_ / CH;
  const int Mc = B_ * CH;

  char* w = (char*)d_ws;
  size_t off = 0;
  auto alloc = [&](size_t bytes) -> void* {
    void* p = (void*)(w + off);
    off += (bytes + 255) & ~(size_t)255;
    return p;
  };
  float*    hE      = (float*)alloc((size_t)32*256*4);
  float*    effb    = (float*)alloc((size_t)32*256*4);
  float*    hstate  = (float*)alloc((size_t)32*512*4);
  __half*   effW    = (__half*)alloc((size_t)32*256*512*2);
  __half*   Wih16   = (__half*)alloc((size_t)1536*512*2);
  __half*   postW16 = (__half*)alloc((size_t)512*512*2);
  uint4*    Wp      = (uint4*)alloc((size_t)8*32*384*16 + 4096);
  unsigned long long* xch64 = (unsigned long long*)alloc((size_t)2*32*256*8);
  __half*   xpre    = (__half*)alloc((size_t)Mc*512*2);
  __half*   gibuf   = (__half*)alloc((size_t)Mc*1536*2);
  __half*   ysbuf   = (__half*)alloc((size_t)Mc*512*2);
  __half*   postc   = xpre;   // xpre dead after gi GEMM

  hyper1<<<32, 256, 0, stream>>>(es, hypW1, hypb1, hE);
  hyper2<<<32, 256, 0, stream>>>(hE, Wbh, bbh, harmb, Wbn, bbn, noiseb, effb);
  hyper3<<<200, 256, 0, stream>>>(hE, Wdh, bdh, harmW, effW, 0);
  hyper3<<<130, 256, 0, stream>>>(hE, Wdn, bdn, noiseW, effW, NH_);
  cvt_f16<<<(1536*512)/256, 256, 0, stream>>>(Wih, Wih16, 1536*512);
  cvt_f16<<<(512*512)/256, 256, 0, stream>>>(postW, postW16, 512*512);
  pack_whh4<<<384, 256, 0, stream>>>(Whh, Wp);

  for (int c = 0; c < NC; ++c) {
    int c0 = c * CH;
    pre_kernel<<<dim3(CH*2, 32), 256, 0, stream>>>(f0, loud, preW, preb, xpre, CH, c0);
    gemm_nt<0><<<dim3(Mc/128, 12), 256, 0, stream>>>(xpre, Wih16, gibuf, b_ih, 1536);
    gru_scan8<<<256, 512, 0, stream>>>(Wp, gibuf, b_hh, ysbuf, hstate, xch64,
                                       CH, c == 0 ? 1 : 0);
    gemm_nt<1><<<dim3(Mc/128, 4), 256, 0, stream>>>(ysbuf, postW16, postc, postb, 512);
    heads_gemm<<<dim3((CH+127)/128, 2, 32), 256, 0, stream>>>(postc, effW, effb,
                                                              (float*)d_out, CH, c0);
  }
}

// Round 15
// 4247.655 us; speedup vs baseline: 1.2728x; 1.0587x over previous
//
#include <hip/hip_runtime.h>
#include <hip/hip_fp16.h>
#include <stdint.h>

#define B_  32
#define T_  2000
#define H_  512
#define NH_ 100
#define NM_ 65

typedef _Float16 f16x8 __attribute__((ext_vector_type(8)));
typedef _Float16 f16x2 __attribute__((ext_vector_type(2)));
typedef float    f32x4 __attribute__((ext_vector_type(4)));

typedef __attribute__((address_space(3))) void lds_void_t;
typedef __attribute__((address_space(1))) void glb_void_t;

__device__ __forceinline__ void gload_lds16(const void* g, void* l) {
  __builtin_amdgcn_global_load_lds((const glb_void_t*)g, (lds_void_t*)l, 16, 0, 0);
}

__device__ __forceinline__ float sigmoidf_(float x) {
  float e = __builtin_amdgcn_exp2f(-x * 1.44269504f);
  return __builtin_amdgcn_rcpf(1.0f + e);
}
__device__ __forceinline__ float tanhf_(float x) {
  float e = __builtin_amdgcn_exp2f(x * 2.88539008f);
  return 1.0f - 2.0f * __builtin_amdgcn_rcpf(e + 1.0f);
}
__device__ __forceinline__ float dot2(unsigned w, unsigned h, float acc) {
  return __builtin_amdgcn_fdot2(__builtin_bit_cast(f16x2, w),
                                __builtin_bit_cast(f16x2, h), acc, false);
}
__device__ __forceinline__ unsigned pack2(float a, float b) {
  __half2 h = __floats2half2_rn(a, b);
  return __builtin_bit_cast(unsigned, h);
}
__device__ __forceinline__ float hsel(unsigned w, int hi) {
  __half2 h2 = __builtin_bit_cast(__half2, w);
  return hi ? __high2float(h2) : __low2float(h2);
}
__device__ __forceinline__ int hq_swz(int i) {
  int cs = i >> 5, kk = (i >> 2) & 7;
  return cs*32 + ((kk ^ cs) << 2) + (i & 3);
}

// ---------------- hypernetwork ----------------
__global__ void hyper1(const float* __restrict__ es, const float* __restrict__ W1,
                       const float* __restrict__ b1, float* __restrict__ hE) {
  int b = blockIdx.x, o = threadIdx.x;   // 32 x 256
  float a = b1[o];
  #pragma unroll
  for (int c = 0; c < 16; ++c) a += es[b*16 + c] * W1[o*16 + c];
  hE[b*256 + o] = fmaxf(a, 0.f);
}

__global__ void hyper2(const float* __restrict__ hE,
                       const float* __restrict__ Wbh, const float* __restrict__ bbh,
                       const float* __restrict__ harmb,
                       const float* __restrict__ Wbn, const float* __restrict__ bbn,
                       const float* __restrict__ noiseb, float* __restrict__ effb) {
  int b = blockIdx.x, o = threadIdx.x;
  if (o < NH_) {
    float a = bbh[o] + harmb[o];
    for (int c = 0; c < 256; ++c) a += hE[b*256 + c] * Wbh[o*256 + c];
    effb[b*256 + o] = a;
  } else if (o < NH_ + NM_) {
    int q = o - NH_;
    float a = bbn[q] + noiseb[q];
    for (int c = 0; c < 256; ++c) a += hE[b*256 + c] * Wbn[q*256 + c];
    effb[b*256 + o] = a;
  }
}

// effW[b][o_base+o][h] = baseW[o*512+h] + bd[row] + sum_c Wd[row][c]*hE[b][c]
__global__ __launch_bounds__(256) void hyper3(
    const float* __restrict__ hE, const float* __restrict__ Wd,
    const float* __restrict__ bd, const float* __restrict__ baseW,
    __half* __restrict__ effW, int o_base) {
  __shared__ float wl[256*33];
  __shared__ float hEl[32*256];
  int tid = threadIdx.x;
  int row0 = blockIdx.x * 256;
  #pragma unroll
  for (int i = 0; i < 32; ++i) hEl[i*256 + tid] = hE[i*256 + tid];
  float acc[32];
  #pragma unroll
  for (int b = 0; b < 32; ++b) acc[b] = 0.f;
  for (int cc = 0; cc < 256; cc += 32) {
    __syncthreads();
    #pragma unroll
    for (int i = 0; i < 32; ++i) {
      int idx = i*256 + tid;
      int r = idx >> 5, c = idx & 31;
      wl[r*33 + c] = Wd[(size_t)(row0 + r)*256 + cc + c];
    }
    __syncthreads();
    #pragma unroll
    for (int c = 0; c < 32; ++c) {
      float w = wl[tid*33 + c];
      #pragma unroll
      for (int b = 0; b < 32; ++b) acc[b] += w * hEl[b*256 + cc + c];
    }
  }
  int row = row0 + tid;
  int o = row >> 9, h = row & 511;
  float base = baseW[row] + bd[row];
  #pragma unroll
  for (int b = 0; b < 32; ++b) {
    effW[((size_t)b*256 + o_base + o)*512 + h] = (__half)(acc[b] + base);
  }
}

// ---------------- converts ----------------
__global__ void cvt_f16(const float* __restrict__ in, __half* __restrict__ out, int n) {
  int i = blockIdx.x*256 + threadIdx.x;
  if (i < n) out[i] = (__half)in[i];
}

// Wp4[(w*32 + k)*384 + t]: thread t = rq*8+cs owns 4 rows x 64 cols.
// k = j*8 + kk: row = (rq>>4)*512 + w*64 + (rq&15)*4 + j, cols = cs*64 + kk*8 ..+8
__global__ void pack_whh4(const float* __restrict__ Whh, uint4* __restrict__ Wp) {
  int idx = blockIdx.x*256 + threadIdx.x;    // 8*32*384 = 98304
  int t = idx % 384;
  int k = (idx / 384) & 31;
  int w = idx / (384*32);
  int rq = t >> 3, cs = t & 7;
  int j = k >> 3, kk = k & 7;
  int row = (rq >> 4)*512 + w*64 + (rq & 15)*4 + j;
  int col0 = cs*64 + kk*8;
  const float* src = Whh + (size_t)row*512 + col0;
  uint4 o;
  o.x = pack2(src[0], src[1]);
  o.y = pack2(src[2], src[3]);
  o.z = pack2(src[4], src[5]);
  o.w = pack2(src[6], src[7]);
  Wp[idx] = o;
}

// ---------------- pre layer (per chunk) ----------------
__global__ void pre_kernel(const float* __restrict__ f0, const float* __restrict__ loud,
                           const float* __restrict__ preW, const float* __restrict__ preb,
                           __half* __restrict__ xpre, int CH, int c0) {
  int b = blockIdx.y;
  int idx = blockIdx.x*256 + threadIdx.x;    // CH*512
  int t = idx >> 9, h = idx & 511;
  int mg = b*T_ + c0 + t;
  float v = f0[mg]*preW[h*2+0] + loud[mg]*preW[h*2+1] + preb[h];
  v = v >= 0.f ? v : 0.01f*v;
  xpre[((size_t)b*CH + t)*512 + h] = (__half)v;
}

// ---------------- trunk GEMM (NT, K=512, 128x128 tile, f16 MFMA) ----------------
template<int ACT>
__global__ __launch_bounds__(256) void gemm_nt(
    const __half* __restrict__ A, const __half* __restrict__ B,
    __half* __restrict__ C, const float* __restrict__ bias, int N) {
  constexpr int K = 512;
  __shared__ __align__(16) __half As[128*64];
  __shared__ __align__(16) __half Bs[128*64];
  int tid = threadIdx.x;
  int bx = blockIdx.x, by = blockIdx.y;
  const __half* Ab = A + (size_t)bx*128*K;
  const __half* Bb = B + (size_t)by*128*K;
  f32x4 acc[4][4] = {};
  int lane = tid & 63;
  int wv = tid >> 6, wr = wv >> 1, wc = wv & 1;
  int lr = lane & 15, lk = lane >> 4;

  for (int kt = 0; kt < K/64; ++kt) {
    #pragma unroll
    for (int j = 0; j < 4; ++j) {
      int idx = j*256 + tid;
      int row = idx >> 3, seg = idx & 7;
      const __half* gpA = Ab + (size_t)row*K + kt*64 + seg*8;
      const __half* gpB = Bb + (size_t)row*K + kt*64 + seg*8;
      __half* lpA = As + (size_t)(j*256 + (tid & ~63))*8;
      __half* lpB = Bs + (size_t)(j*256 + (tid & ~63))*8;
      gload_lds16(gpA, lpA);
      gload_lds16(gpB, lpB);
    }
    __syncthreads();
    #pragma unroll
    for (int ks = 0; ks < 2; ++ks) {
      f16x8 af[4], bf[4];
      #pragma unroll
      for (int i = 0; i < 4; ++i)
        af[i] = *(const f16x8*)(As + (wr*64 + i*16 + lr)*64 + ks*32 + lk*8);
      #pragma unroll
      for (int j2 = 0; j2 < 4; ++j2)
        bf[j2] = *(const f16x8*)(Bs + (wc*64 + j2*16 + lr)*64 + ks*32 + lk*8);
      #pragma unroll
      for (int i = 0; i < 4; ++i)
        #pragma unroll
        for (int j2 = 0; j2 < 4; ++j2)
          acc[i][j2] = __builtin_amdgcn_mfma_f32_16x16x32_f16(af[i], bf[j2], acc[i][j2], 0, 0, 0);
    }
    __syncthreads();
  }

  #pragma unroll
  for (int j2 = 0; j2 < 4; ++j2) {
    int col = by*128 + wc*64 + j2*16 + lr;
    float bv = bias[col];
    #pragma unroll
    for (int i = 0; i < 4; ++i) {
      int row0 = bx*128 + wr*64 + i*16 + lk*4;
      #pragma unroll
      for (int r = 0; r < 4; ++r) {
        float v = acc[i][j2][r] + bv;
        if (ACT == 1) v = v >= 0.f ? v : 0.01f*v;
        C[(size_t)(row0 + r)*N + col] = (__half)v;
      }
    }
  }
}

// ---------------- heads GEMM: per-batch modulated weights, sigmoid, fp32 out ----------------
__global__ __launch_bounds__(256) void heads_gemm(
    const __half* __restrict__ Apc, const __half* __restrict__ effW,
    const float* __restrict__ effb, float* __restrict__ out, int CH, int c0) {
  constexpr int K = 512;
  __shared__ __align__(16) __half As[128*64];
  __shared__ __align__(16) __half Bs[128*64];
  int tid = threadIdx.x;
  int bx = blockIdx.x, by = blockIdx.y, b = blockIdx.z;
  const __half* Ab = Apc + (size_t)b*CH*K;
  const __half* Bb = effW + ((size_t)b*256 + (size_t)by*128)*K;
  f32x4 acc[4][4] = {};
  int lane = tid & 63;
  int wv = tid >> 6, wr = wv >> 1, wc = wv & 1;
  int lr = lane & 15, lk = lane >> 4;

  for (int kt = 0; kt < K/64; ++kt) {
    #pragma unroll
    for (int j = 0; j < 4; ++j) {
      int idx = j*256 + tid;
      int row = idx >> 3, seg = idx & 7;
      int ar = bx*128 + row; if (ar > CH-1) ar = CH-1;
      const __half* gpA = Ab + (size_t)ar*K + kt*64 + seg*8;
      const __half* gpB = Bb + (size_t)row*K + kt*64 + seg*8;
      __half* lpA = As + (size_t)(j*256 + (tid & ~63))*8;
      __half* lpB = Bs + (size_t)(j*256 + (tid & ~63))*8;
      gload_lds16(gpA, lpA);
      gload_lds16(gpB, lpB);
    }
    __syncthreads();
    #pragma unroll
    for (int ks = 0; ks < 2; ++ks) {
      f16x8 af[4], bf[4];
      #pragma unroll
      for (int i = 0; i < 4; ++i)
        af[i] = *(const f16x8*)(As + (wr*64 + i*16 + lr)*64 + ks*32 + lk*8);
      #pragma unroll
      for (int j2 = 0; j2 < 4; ++j2)
        bf[j2] = *(const f16x8*)(Bs + (wc*64 + j2*16 + lr)*64 + ks*32 + lk*8);
      #pragma unroll
      for (int i = 0; i < 4; ++i)
        #pragma unroll
        for (int j2 = 0; j2 < 4; ++j2)
          acc[i][j2] = __builtin_amdgcn_mfma_f32_16x16x32_f16(af[i], bf[j2], acc[i][j2], 0, 0, 0);
    }
    __syncthreads();
  }

  #pragma unroll
  for (int j2 = 0; j2 < 4; ++j2) {
    int o = by*128 + wc*64 + j2*16 + lr;
    if (o < NH_ + NM_) {
      float bv = effb[b*256 + o];
      #pragma unroll
      for (int i = 0; i < 4; ++i) {
        #pragma unroll
        for (int r = 0; r < 4; ++r) {
          int trow = bx*128 + wr*64 + i*16 + lk*4 + r;
          if (trow < CH) {
            int tg = c0 + trow;
            float v = sigmoidf_(acc[i][j2][r] + bv);
            if (o < NH_)
              out[((size_t)b*T_ + tg)*NH_ + o] = v;
            else
              out[(size_t)B_*T_*NH_ + ((size_t)b*T_ + tg)*NM_ + (o - NH_)] = v;
          }
        }
      }
    }
  }
}

// ---------------- GRU scan: 8 WGs/batch, 4rows x 64cols gemv, u64 tagged exchange ----
// FINAL (empirical best, reverted r9): cross-CU recurrence is LATENCY-bound on
// the publish->detect round trip through the device coherence point (~1.1us/step,
// invariant under barrier restructure r8, DPP r10, L2 mailboxes r11/r13, poll
// cadence r14). H=512 weights (1.57MB f16) are 3x the per-CU register file, so
// the per-step cross-CU exchange is unavoidable; 2000 serial steps x ~2600cy
// is the structural floor for this recurrence on this part.
#define LOADW(k) { const uint4* p = Wp + ((size_t)(w*32 + (k)))*384 + t; \
  asm volatile("global_load_dwordx4 %0, %1, off" : "=v"(wq_##k) : "v"(p) : "memory"); }

#define DOT4(k, hv, A) { \
  A = dot2(wq_##k.x, hv.x, A); A = dot2(wq_##k.y, hv.y, A); \
  A = dot2(wq_##k.z, hv.z, A); A = dot2(wq_##k.w, hv.w, A); }

#define BARX() do { asm volatile("s_waitcnt lgkmcnt(0)\n\ts_barrier" ::: "memory"); \
                    __builtin_amdgcn_sched_barrier(0); } while (0)

__global__ __launch_bounds__(512) __attribute__((amdgpu_waves_per_eu(2, 4)))
void gru_scan8(
    const uint4* __restrict__ Wp, const __half* __restrict__ gi_c,
    const float* __restrict__ bhh, __half* __restrict__ ys_c,
    float* __restrict__ hstate, unsigned long long* __restrict__ xch64,
    int CH, int first) {
  int wg = blockIdx.x;
  int b = wg & 31;            // batch
  int w = wg >> 5;            // unit-block 0..7 (units w*64 .. +64)
  int t = threadIdx.x;
  int rq = t >> 3, cs = t & 7;
  bool wact = (t < 384);      // waves 0-5 hold weights
  bool comb = (t >= 384 && t < 416);   // wave 6 lower half: combine
  int tc = t - 384;           // combine lane (units 2tc, 2tc+1)

  __shared__ __align__(16) unsigned hq[256];   // h packed f16x2, swizzled (hq_swz)
  __shared__ float part[192];                  // fully-reduced gate partials [g*64+u]
  __shared__ float gil[192];                   // gi slices for combine

  uint4 wq_0{},wq_1{},wq_2{},wq_3{},wq_4{},wq_5{},wq_6{},wq_7{},
        wq_8{},wq_9{},wq_10{},wq_11{},wq_12{},wq_13{},wq_14{},wq_15{},
        wq_16{},wq_17{},wq_18{},wq_19{},wq_20{},wq_21{},wq_22{},wq_23{},
        wq_24{},wq_25{},wq_26{},wq_27{},wq_28{},wq_29{},wq_30{},wq_31{};
  if (wact) {
    LOADW(0)  LOADW(1)  LOADW(2)  LOADW(3)  LOADW(4)  LOADW(5)  LOADW(6)  LOADW(7)
    LOADW(8)  LOADW(9)  LOADW(10) LOADW(11) LOADW(12) LOADW(13) LOADW(14) LOADW(15)
    LOADW(16) LOADW(17) LOADW(18) LOADW(19) LOADW(20) LOADW(21) LOADW(22) LOADW(23)
    LOADW(24) LOADW(25) LOADW(26) LOADW(27) LOADW(28) LOADW(29) LOADW(30) LOADW(31)
  }
  asm volatile("s_waitcnt vmcnt(0)" ::: "memory");
  __builtin_amdgcn_sched_barrier(0);

  // combine-wave biases (tc handles units 2tc, 2tc+1)
  float br0=0.f,br1=0.f,bz0=0.f,bz1=0.f,bn0=0.f,bn1=0.f;
  if (comb) {
    int u0 = w*64 + 2*tc;
    br0 = bhh[u0];        br1 = bhh[u0+1];
    bz0 = bhh[512+u0];    bz1 = bhh[512+u0+1];
    bn0 = bhh[1024+u0];   bn1 = bhh[1024+u0+1];
  }

  if (t < 256) {
    unsigned hv0 = first ? 0u : pack2(hstate[b*512 + 2*t], hstate[b*512 + 2*t + 1]);
    hq[hq_swz(t)] = hv0;
  }
  __syncthreads();

  const __half* gib = gi_c + (size_t)b*CH*1536;
  __half* ysb = ys_c + (size_t)b*CH*512;
  const uint4* hq4 = (const uint4*)hq;
  int hb = cs*8;

  // gi prefetch: giv_cur holds step-s value; load s+1 at loop top
  float giv_cur = 0.f, giv_next = 0.f;
  if (t < 192) giv_cur = (float)gib[(t >> 6)*512 + w*64 + (t & 63)];

  for (int s = 0; s < CH; ++s) {
    int p = s & 1;
    unsigned long long* xp64 = xch64 + ((size_t)p*32 + b)*256;

    if (t < 192 && s + 1 < CH)
      giv_next = (float)gib[(size_t)(s+1)*1536 + (t >> 6)*512 + w*64 + (t & 63)];

    if (wact) {
      uint4 hv0_ = hq4[hb + (0 ^ cs)];
      uint4 hv1_ = hq4[hb + (1 ^ cs)];
      uint4 hv2_ = hq4[hb + (2 ^ cs)];
      uint4 hv3_ = hq4[hb + (3 ^ cs)];
      uint4 hv4_ = hq4[hb + (4 ^ cs)];
      uint4 hv5_ = hq4[hb + (5 ^ cs)];
      uint4 hv6_ = hq4[hb + (6 ^ cs)];
      uint4 hv7_ = hq4[hb + (7 ^ cs)];
      float a0 = 0.f, a1 = 0.f, a2 = 0.f, a3 = 0.f;
      DOT4(0,hv0_,a0)  DOT4(8,hv0_,a1)  DOT4(16,hv0_,a2) DOT4(24,hv0_,a3)
      DOT4(1,hv1_,a0)  DOT4(9,hv1_,a1)  DOT4(17,hv1_,a2) DOT4(25,hv1_,a3)
      DOT4(2,hv2_,a0)  DOT4(10,hv2_,a1) DOT4(18,hv2_,a2) DOT4(26,hv2_,a3)
      DOT4(3,hv3_,a0)  DOT4(11,hv3_,a1) DOT4(19,hv3_,a2) DOT4(27,hv3_,a3)
      DOT4(4,hv4_,a0)  DOT4(12,hv4_,a1) DOT4(20,hv4_,a2) DOT4(28,hv4_,a3)
      DOT4(5,hv5_,a0)  DOT4(13,hv5_,a1) DOT4(21,hv5_,a2) DOT4(29,hv5_,a3)
      DOT4(6,hv6_,a0)  DOT4(14,hv6_,a1) DOT4(22,hv6_,a2) DOT4(30,hv6_,a3)
      DOT4(7,hv7_,a0)  DOT4(15,hv7_,a1) DOT4(23,hv7_,a2) DOT4(31,hv7_,a3)
      // in-wave 8-way column reduce (cs lanes are adjacent: xor 1,2,4 stay in group)
      a0 += __shfl_xor(a0, 1); a0 += __shfl_xor(a0, 2); a0 += __shfl_xor(a0, 4);
      a1 += __shfl_xor(a1, 1); a1 += __shfl_xor(a1, 2); a1 += __shfl_xor(a1, 4);
      a2 += __shfl_xor(a2, 1); a2 += __shfl_xor(a2, 2); a2 += __shfl_xor(a2, 4);
      a3 += __shfl_xor(a3, 1); a3 += __shfl_xor(a3, 2); a3 += __shfl_xor(a3, 4);
      if (cs < 4) {
        float v = (cs == 0) ? a0 : (cs == 1) ? a1 : (cs == 2) ? a2 : a3;
        part[(rq << 2) + cs] = v;
      }
      if (t < 192) gil[t] = giv_cur;
    }
    giv_cur = giv_next;
    BARX();   // B1: part + gil visible

    if (comb) {
      int j0 = 2*tc, j1 = 2*tc + 1;
      float r0 = sigmoidf_(gil[j0] + part[j0] + br0);
      float r1 = sigmoidf_(gil[j1] + part[j1] + br1);
      float z0 = sigmoidf_(gil[64+j0] + part[64+j0] + bz0);
      float z1 = sigmoidf_(gil[64+j1] + part[64+j1] + bz1);
      float n0 = tanhf_(gil[128+j0] + r0*(part[128+j0] + bn0));
      float n1 = tanhf_(gil[128+j1] + r1*(part[128+j1] + bn1));
      int gidx = w*32 + tc;
      int hidx = hq_swz(gidx);
      unsigned hold = hq[hidx];
      float h0 = (1.f - z0)*n0 + z0*hsel(hold, 0);
      float h1 = (1.f - z1)*n1 + z1*hsel(hold, 1);
      unsigned hv = pack2(h0, h1);
      hq[hidx] = hv;                                              // own slice -> LDS
      *(unsigned*)&ysb[(size_t)s*512 + w*64 + j0] = hv;           // ys (background)
      unsigned long long tv = ((unsigned long long)(unsigned)(s + 1) << 32)
                              | (unsigned long long)hv;
      __hip_atomic_store(&xp64[gidx], tv,
                         __ATOMIC_RELAXED, __HIP_MEMORY_SCOPE_AGENT);
      if (s == CH - 1) {
        hstate[b*512 + w*64 + j0] = h0;
        hstate[b*512 + w*64 + j1] = h1;
      }
    } else if (t < 256 && (t >> 5) != w) {
      unsigned long long v;
      do {
        v = __hip_atomic_load(&xp64[t], __ATOMIC_RELAXED, __HIP_MEMORY_SCOPE_AGENT);
      } while ((unsigned)(v >> 32) != (unsigned)(s + 1));
      hq[hq_swz(t)] = (unsigned)v;
    }
    BARX();   // B2: hq complete for next gemv
  }
}

// ---------------- launch ----------------
extern "C" void kernel_launch(void* const* d_in, const int* in_sizes, int n_in,
                              void* d_out, int out_size, void* d_ws, size_t ws_size,
                              hipStream_t stream) {
  const float* f0     = (const float*)d_in[0];
  const float* loud   = (const float*)d_in[1];
  const float* es     = (const float*)d_in[2];
  const float* preW   = (const float*)d_in[3];
  const float* preb   = (const float*)d_in[4];
  const float* Wih    = (const float*)d_in[5];
  const float* Whh    = (const float*)d_in[6];
  const float* b_ih   = (const float*)d_in[7];
  const float* b_hh   = (const float*)d_in[8];
  const float* postW  = (const float*)d_in[9];
  const float* postb  = (const float*)d_in[10];
  const float* harmW  = (const float*)d_in[11];
  const float* harmb  = (const float*)d_in[12];
  const float* noiseW = (const float*)d_in[13];
  const float* noiseb = (const float*)d_in[14];
  const float* hypW1  = (const float*)d_in[15];
  const float* hypb1  = (const float*)d_in[16];
  const float* Wdh    = (const float*)d_in[17];
  const float* bdh    = (const float*)d_in[18];
  const float* Wbh    = (const float*)d_in[19];
  const float* bbh    = (const float*)d_in[20];
  const float* Wdn    = (const float*)d_in[21];
  const float* bdn    = (const float*)d_in[22];
  const float* Wbn    = (const float*)d_in[23];
  const float* bbn    = (const float*)d_in[24];
  (void)in_sizes; (void)n_in; (void)out_size;

  const size_t FIXED = 13312ull*1024ull;   // ~13 MB fixed region
  int CH = 20;
  {
    const int opts[8] = {2000, 1000, 500, 400, 200, 100, 40, 20};
    for (int i = 0; i < 8; ++i) {
      size_t need = FIXED + (size_t)opts[i] * 163840ull + 65536ull;
      if (need <= ws_size) { CH = opts[i]; break; }
    }
  }
  const int NC = T_ / CH;
  const int Mc = B_ * CH;

  char* w = (char*)d_ws;
  size_t off = 0;
  auto alloc = [&](size_t bytes) -> void* {
    void* p = (void*)(w + off);
    off += (bytes + 255) & ~(size_t)255;
    return p;
  };
  float*    hE      = (float*)alloc((size_t)32*256*4);
  float*    effb    = (float*)alloc((size_t)32*256*4);
  float*    hstate  = (float*)alloc((size_t)32*512*4);
  __half*   effW    = (__half*)alloc((size_t)32*256*512*2);
  __half*   Wih16   = (__half*)alloc((size_t)1536*512*2);
  __half*   postW16 = (__half*)alloc((size_t)512*512*2);
  uint4*    Wp      = (uint4*)alloc((size_t)8*32*384*16 + 4096);
  unsigned long long* xch64 = (unsigned long long*)alloc((size_t)2*32*256*8);
  __half*   xpre    = (__half*)alloc((size_t)Mc*512*2);
  __half*   gibuf   = (__half*)alloc((size_t)Mc*1536*2);
  __half*   ysbuf   = (__half*)alloc((size_t)Mc*512*2);
  __half*   postc   = xpre;   // xpre dead after gi GEMM

  hyper1<<<32, 256, 0, stream>>>(es, hypW1, hypb1, hE);
  hyper2<<<32, 256, 0, stream>>>(hE, Wbh, bbh, harmb, Wbn, bbn, noiseb, effb);
  hyper3<<<200, 256, 0, stream>>>(hE, Wdh, bdh, harmW, effW, 0);
  hyper3<<<130, 256, 0, stream>>>(hE, Wdn, bdn, noiseW, effW, NH_);
  cvt_f16<<<(1536*512)/256, 256, 0, stream>>>(Wih, Wih16, 1536*512);
  cvt_f16<<<(512*512)/256, 256, 0, stream>>>(postW, postW16, 512*512);
  pack_whh4<<<384, 256, 0, stream>>>(Whh, Wp);

  for (int c = 0; c < NC; ++c) {
    int c0 = c * CH;
    pre_kernel<<<dim3(CH*2, 32), 256, 0, stream>>>(f0, loud, preW, preb, xpre, CH, c0);
    gemm_nt<0><<<dim3(Mc/128, 12), 256, 0, stream>>>(xpre, Wih16, gibuf, b_ih, 1536);
    gru_scan8<<<256, 512, 0, stream>>>(Wp, gibuf, b_hh, ysbuf, hstate, xch64,
                                       CH, c == 0 ? 1 : 0);
    gemm_nt<1><<<dim3(Mc/128, 4), 256, 0, stream>>>(ysbuf, postW16, postc, postb, 512);
    heads_gemm<<<dim3((CH+127)/128, 2, 32), 256, 0, stream>>>(postc, effW, effb,
                                                              (float*)d_out, CH, c0);
  }
}